// Round 2
// baseline (361.338 us; speedup 1.0000x reference)
//
#include <hip/hip_runtime.h>
#include <stdint.h>

typedef __attribute__((ext_vector_type(8))) short bf16x8;
typedef __attribute__((ext_vector_type(4))) short bf16x4;
typedef __attribute__((ext_vector_type(4))) float f32x4;
typedef __attribute__((ext_vector_type(4))) unsigned short u16x4;

__device__ __forceinline__ unsigned short f2bf(float f) {
  union { float f; unsigned u; } x; x.f = f;
  unsigned r = x.u + 0x7FFFu + ((x.u >> 16) & 1u);
  return (unsigned short)(r >> 16);
}

// ---------------- fp32 -> bf16 convert (x4 vectorized) ----------------
__global__ __launch_bounds__(256) void k_cvt(const float* __restrict__ in,
                                             unsigned short* __restrict__ out, int n4) {
  int i = blockIdx.x * 256 + threadIdx.x;
  if (i >= n4) return;
  f32x4 v = reinterpret_cast<const f32x4*>(in)[i];
  u16x4 o;
  o[0] = f2bf(v[0]); o[1] = f2bf(v[1]); o[2] = f2bf(v[2]); o[3] = f2bf(v[3]);
  reinterpret_cast<u16x4*>(out)[i] = o;
}

// ---------------- RoPE cos/sin tables: (256, 64) ----------------
// F[n][d] = (d<32 ? (n>>4) : (n&15)) * 10000^(-((d&31)>>1)/16)
__global__ void k_tables(float* __restrict__ cosT, float* __restrict__ sinT) {
  int n = threadIdx.x;
  int r = n >> 4, cc = n & 15;
  for (int d = 0; d < 64; ++d) {
    int tpos = (d < 32) ? r : cc;
    int j = (d & 31) >> 1;
    float ang = (float)tpos * powf(10000.0f, -(float)j * (1.0f / 16.0f));
    cosT[n * 64 + d] = cosf(ang);
    sinT[n * 64 + d] = sinf(ang);
  }
}

// ---------------- 128x128x(BK=32) bf16 MFMA GEMM, B^T input ----------------
// EPI==0: qkv output -> RoPE(q,k)+scale(q), scatter to q/k (B,H,N,D) and vT (B,H,D,N)
// EPI==1: proj output -> +bias, fp32 to d_out
template <int EPI>
__global__ __launch_bounds__(256) void k_gemm(
    const unsigned short* __restrict__ A,  // M x K bf16
    const unsigned short* __restrict__ B,  // N x K bf16 (B^T layout)
    int M, int N, int K, int nTM,
    const float* __restrict__ cosT, const float* __restrict__ sinT,
    unsigned short* __restrict__ qout, unsigned short* __restrict__ kout,
    unsigned short* __restrict__ vTout,
    const float* __restrict__ bias, float* __restrict__ fout) {
  constexpr int LDT = 40;  // 32 + 8 pad (keeps 16B alignment, kills most bank conflicts)
  __shared__ unsigned short Al[128 * LDT];
  __shared__ unsigned short Bl[128 * LDT];
  const int tm = blockIdx.x % nTM, tn = blockIdx.x / nTM;
  const int m0 = tm * 128, n0 = tn * 128;
  const int t = threadIdx.x, w = t >> 6, l = t & 63, c = l & 15, g = l >> 4;
  const int wm = w >> 1, wn = w & 1;

  f32x4 acc[4][4];
#pragma unroll
  for (int i = 0; i < 4; ++i)
#pragma unroll
    for (int j = 0; j < 4; ++j) acc[i][j] = 0.0f;

  const int rr = t >> 2;           // 0..63
  const int cc8 = (t & 3) * 8;     // element col within BK

  for (int kt = 0; kt < K; kt += 32) {
#pragma unroll
    for (int i = 0; i < 2; ++i) {
      int r = i * 64 + rr;
      bf16x8 av = *reinterpret_cast<const bf16x8*>(A + (size_t)(m0 + r) * K + kt + cc8);
      bf16x8 bv = *reinterpret_cast<const bf16x8*>(B + (size_t)(n0 + r) * K + kt + cc8);
      *reinterpret_cast<bf16x8*>(&Al[r * LDT + cc8]) = av;
      *reinterpret_cast<bf16x8*>(&Bl[r * LDT + cc8]) = bv;
    }
    __syncthreads();
    bf16x8 af[4], bfr[4];
#pragma unroll
    for (int mf = 0; mf < 4; ++mf)
      af[mf] = *reinterpret_cast<const bf16x8*>(&Al[(wm * 64 + mf * 16 + c) * LDT + g * 8]);
#pragma unroll
    for (int nf = 0; nf < 4; ++nf)
      bfr[nf] = *reinterpret_cast<const bf16x8*>(&Bl[(wn * 64 + nf * 16 + c) * LDT + g * 8]);
#pragma unroll
    for (int mf = 0; mf < 4; ++mf)
#pragma unroll
      for (int nf = 0; nf < 4; ++nf)
        acc[mf][nf] = __builtin_amdgcn_mfma_f32_16x16x32_bf16(af[mf], bfr[nf], acc[mf][nf], 0, 0, 0);
    __syncthreads();
  }

  if constexpr (EPI == 0) {
    const int which = n0 >> 10;  // 0=q 1=k 2=v (uniform per block: 1024 % 128 == 0)
    unsigned short* qk = (which == 0) ? qout : kout;
#pragma unroll
    for (int nf = 0; nf < 4; ++nf) {
      const int o = n0 + wn * 64 + nf * 16 + c;
      const int h = (o >> 6) & 15;
      const int d = o & 63;
      if (which < 2) {
        const float sgn = (d & 1) ? 1.0f : -1.0f;  // even d: -x_odd*sin; odd d: +x_even*sin
        const float qscale = (which == 0) ? 0.125f : 1.0f;  // fold D^-0.5 into q
#pragma unroll
        for (int mf = 0; mf < 4; ++mf) {
          const int m = m0 + wm * 64 + mf * 16 + g * 4;
          const int bb = m >> 8;
          const int nb = m & 255;  // m%4==0 so nb+j never crosses 256
          f32x4 v = acc[mf][nf];
          f32x4 p;
          p[0] = __shfl_xor(v[0], 1);
          p[1] = __shfl_xor(v[1], 1);
          p[2] = __shfl_xor(v[2], 1);
          p[3] = __shfl_xor(v[3], 1);
          size_t base = ((size_t)(bb * 16 + h) * 256 + nb) * 64 + d;
#pragma unroll
          for (int j = 0; j < 4; ++j) {
            const int n = nb + j;
            const float cv = cosT[n * 64 + d];
            const float sv = sinT[n * 64 + d];
            float ov = (v[j] * cv + sgn * p[j] * sv) * qscale;
            qk[base + (size_t)j * 64] = f2bf(ov);
          }
        }
      } else {
#pragma unroll
        for (int mf = 0; mf < 4; ++mf) {
          const int m = m0 + wm * 64 + mf * 16 + g * 4;
          const int bb = m >> 8;
          const int nb = m & 255;
          f32x4 v = acc[mf][nf];
          u16x4 pk;
          pk[0] = f2bf(v[0]); pk[1] = f2bf(v[1]); pk[2] = f2bf(v[2]); pk[3] = f2bf(v[3]);
          size_t idx = ((size_t)(bb * 16 + h) * 64 + d) * 256 + nb;  // vT[b,h,d,n]
          *reinterpret_cast<u16x4*>(vTout + idx) = pk;
        }
      }
    }
  } else {
#pragma unroll
    for (int nf = 0; nf < 4; ++nf) {
      const int o = n0 + wn * 64 + nf * 16 + c;
      const float bv = bias[o];
#pragma unroll
      for (int mf = 0; mf < 4; ++mf) {
        const int m = m0 + wm * 64 + mf * 16 + g * 4;
        f32x4 v = acc[mf][nf];
#pragma unroll
        for (int j = 0; j < 4; ++j) fout[(size_t)(m + j) * N + o] = v[j] + bv;
      }
    }
  }
}

// ---------------- flash attention, swapped operands ----------------
// block = one (b,h); 4 waves, wave w owns q rows [w*64, w*64+64)
// sT = mfma(A=K, B=Q): C frag col = q (lane&15), row = kv -> softmax is lane-local-ish
// outT = mfma(A=V^T, B=P): C frag col = q, row = d
__global__ __launch_bounds__(256) void k_attn(const unsigned short* __restrict__ Q,
                                              const unsigned short* __restrict__ Kb,
                                              const unsigned short* __restrict__ VT,
                                              unsigned short* __restrict__ Out) {
  constexpr int LDK = 80, LDP = 80;
  __shared__ unsigned short klds[64 * LDK];
  __shared__ unsigned short plds[4][64 * LDP];
  const int bh = blockIdx.x;
  const int bb = bh >> 4, h = bh & 15;
  const int t = threadIdx.x, w = t >> 6, l = t & 63, c = l & 15, g = l >> 4;
  const unsigned short* qh = Q + (size_t)bh * 256 * 64;
  const unsigned short* kh = Kb + (size_t)bh * 256 * 64;
  const unsigned short* vh = VT + (size_t)bh * 64 * 256;
  const int q0 = w * 64;

  bf16x8 qf[4][2];
#pragma unroll
  for (int nf = 0; nf < 4; ++nf)
#pragma unroll
    for (int ks = 0; ks < 2; ++ks)
      qf[nf][ks] = *reinterpret_cast<const bf16x8*>(qh + (q0 + nf * 16 + c) * 64 + ks * 32 + g * 8);

  f32x4 oacc[4][4];
#pragma unroll
  for (int i = 0; i < 4; ++i)
#pragma unroll
    for (int j = 0; j < 4; ++j) oacc[i][j] = 0.0f;
  float mr[4] = {-1e30f, -1e30f, -1e30f, -1e30f};
  float lr[4] = {0.f, 0.f, 0.f, 0.f};

  for (int ch = 0; ch < 4; ++ch) {
    __syncthreads();  // everyone done reading previous k chunk
    {
      int row = t >> 3, col = (t & 7) * 8;
#pragma unroll
      for (int rep = 0; rep < 2; ++rep) {
        int r = rep * 32 + row;
        bf16x8 kv = *reinterpret_cast<const bf16x8*>(kh + (ch * 64 + r) * 64 + col);
        *reinterpret_cast<bf16x8*>(&klds[r * LDK + col]) = kv;
      }
    }
    __syncthreads();

    f32x4 s[4][4];
#pragma unroll
    for (int i = 0; i < 4; ++i)
#pragma unroll
      for (int j = 0; j < 4; ++j) s[i][j] = 0.0f;
#pragma unroll
    for (int ks = 0; ks < 2; ++ks) {
      bf16x8 kf[4];
#pragma unroll
      for (int mf = 0; mf < 4; ++mf)
        kf[mf] = *reinterpret_cast<const bf16x8*>(&klds[(mf * 16 + c) * LDK + ks * 32 + g * 8]);
#pragma unroll
      for (int mf = 0; mf < 4; ++mf)
#pragma unroll
        for (int nf = 0; nf < 4; ++nf)
          s[mf][nf] = __builtin_amdgcn_mfma_f32_16x16x32_bf16(kf[mf], qf[nf][ks], s[mf][nf], 0, 0, 0);
    }

    // online softmax per q column (q = 16*nf + c; kv spread over mf, j, and lane groups g)
#pragma unroll
    for (int nf = 0; nf < 4; ++nf) {
      float mx = -1e30f;
#pragma unroll
      for (int mf = 0; mf < 4; ++mf)
#pragma unroll
        for (int j = 0; j < 4; ++j) mx = fmaxf(mx, s[mf][nf][j]);
      mx = fmaxf(mx, __shfl_xor(mx, 16));
      mx = fmaxf(mx, __shfl_xor(mx, 32));
      float mnew = fmaxf(mr[nf], mx);
      float rsc = __expf(mr[nf] - mnew);
      mr[nf] = mnew;
      float sum = 0.f;
#pragma unroll
      for (int mf = 0; mf < 4; ++mf)
#pragma unroll
        for (int j = 0; j < 4; ++j) {
          float p = __expf(s[mf][nf][j] - mnew);
          s[mf][nf][j] = p;
          sum += p;
        }
      sum += __shfl_xor(sum, 16);
      sum += __shfl_xor(sum, 32);
      lr[nf] = lr[nf] * rsc + sum;
#pragma unroll
      for (int mf = 0; mf < 4; ++mf) oacc[mf][nf] *= rsc;
    }

    // P -> per-wave LDS (row = q, col = kv), bf16
#pragma unroll
    for (int mf = 0; mf < 4; ++mf)
#pragma unroll
      for (int nf = 0; nf < 4; ++nf) {
        bf16x4 pk;
        pk[0] = (short)f2bf(s[mf][nf][0]);
        pk[1] = (short)f2bf(s[mf][nf][1]);
        pk[2] = (short)f2bf(s[mf][nf][2]);
        pk[3] = (short)f2bf(s[mf][nf][3]);
        *reinterpret_cast<bf16x4*>(&plds[w][(nf * 16 + c) * LDP + mf * 16 + g * 4]) = pk;
      }

    // PV: outT += V^T(chunk) * P(chunk)
#pragma unroll
    for (int ks = 0; ks < 2; ++ks) {
      bf16x8 vf[4], pf[4];
#pragma unroll
      for (int mf = 0; mf < 4; ++mf)
        vf[mf] = *reinterpret_cast<const bf16x8*>(vh + (mf * 16 + c) * 256 + ch * 64 + ks * 32 + g * 8);
#pragma unroll
      for (int nf = 0; nf < 4; ++nf) {
        bf16x4 p0 = *reinterpret_cast<const bf16x4*>(&plds[w][(nf * 16 + c) * LDP + ks * 32 + g * 8]);
        bf16x4 p1 = *reinterpret_cast<const bf16x4*>(&plds[w][(nf * 16 + c) * LDP + ks * 32 + g * 8 + 4]);
        pf[nf] = __builtin_shufflevector(p0, p1, 0, 1, 2, 3, 4, 5, 6, 7);
      }
#pragma unroll
      for (int mf = 0; mf < 4; ++mf)
#pragma unroll
        for (int nf = 0; nf < 4; ++nf)
          oacc[mf][nf] = __builtin_amdgcn_mfma_f32_16x16x32_bf16(vf[mf], pf[nf], oacc[mf][nf], 0, 0, 0);
    }
  }

  float linv[4];
#pragma unroll
  for (int nf = 0; nf < 4; ++nf) linv[nf] = 1.0f / lr[nf];
#pragma unroll
  for (int mf = 0; mf < 4; ++mf)
#pragma unroll
    for (int nf = 0; nf < 4; ++nf) {
      f32x4 v = oacc[mf][nf];
      u16x4 pk;
      pk[0] = f2bf(v[0] * linv[nf]);
      pk[1] = f2bf(v[1] * linv[nf]);
      pk[2] = f2bf(v[2] * linv[nf]);
      pk[3] = f2bf(v[3] * linv[nf]);
      size_t row = (size_t)bb * 256 + q0 + nf * 16 + c;
      size_t idx = row * 1024 + (size_t)h * 64 + mf * 16 + g * 4;  // out[b,n, h*64+d]
      *reinterpret_cast<u16x4*>(Out + idx) = pk;
    }
}

extern "C" void kernel_launch(void* const* d_in, const int* in_sizes, int n_in,
                              void* d_out, int out_size, void* d_ws, size_t ws_size,
                              hipStream_t stream) {
  const float* x = (const float*)d_in[0];
  const float* wqkv = (const float*)d_in[1];
  const float* wproj = (const float*)d_in[2];
  const float* bproj = (const float*)d_in[3];

  char* ws = (char*)d_ws;
  unsigned short* xb = (unsigned short*)(ws);                 // 33,554,432 B (reused as attn_out)
  unsigned short* wqkvb = (unsigned short*)(ws + 33554432);   //  6,291,456 B
  unsigned short* wprojb = (unsigned short*)(ws + 39845888);  //  2,097,152 B
  float* cosT = (float*)(ws + 41943040);                      //     65,536 B
  float* sinT = (float*)(ws + 42008576);                      //     65,536 B
  unsigned short* qb = (unsigned short*)(ws + 42074112);      // 33,554,432 B
  unsigned short* kb = (unsigned short*)(ws + 75628544);      // 33,554,432 B
  unsigned short* vtb = (unsigned short*)(ws + 109182976);    // 33,554,432 B -> total 142,737,408 B
  unsigned short* attn_out = xb;

  k_cvt<<<16384, 256, 0, stream>>>(x, xb, 4194304);
  k_cvt<<<3072, 256, 0, stream>>>(wqkv, wqkvb, 786432);
  k_cvt<<<1024, 256, 0, stream>>>(wproj, wprojb, 262144);
  k_tables<<<1, 256, 0, stream>>>(cosT, sinT);

  // QKV: M=16384, N=3072, K=1024 (B^T layout), RoPE epilogue
  k_gemm<0><<<128 * 24, 256, 0, stream>>>(xb, wqkvb, 16384, 3072, 1024, 128,
                                          cosT, sinT, qb, kb, vtb, nullptr, nullptr);
  // attention: one block per (b,h)
  k_attn<<<1024, 256, 0, stream>>>(qb, kb, vtb, attn_out);
  // proj: M=16384, N=1024, K=1024, +bias, fp32 out
  k_gemm<1><<<128 * 8, 256, 0, stream>>>(attn_out, wprojb, 16384, 1024, 1024, 128,
                                         nullptr, nullptr, nullptr, nullptr, nullptr,
                                         bproj, (float*)d_out);
}

// Round 3
// 347.832 us; speedup vs baseline: 1.0388x; 1.0388x over previous
//
#include <hip/hip_runtime.h>
#include <stdint.h>

typedef __attribute__((ext_vector_type(8))) short bf16x8;
typedef __attribute__((ext_vector_type(4))) short bf16x4;
typedef __attribute__((ext_vector_type(4))) float f32x4;
typedef __attribute__((ext_vector_type(4))) unsigned short u16x4;

typedef __attribute__((address_space(3))) unsigned short lds_u16;
typedef const __attribute__((address_space(1))) unsigned short glb_u16;

__device__ __forceinline__ unsigned short f2bf(float f) {
  union { float f; unsigned u; } x; x.f = f;
  unsigned r = x.u + 0x7FFFu + ((x.u >> 16) & 1u);
  return (unsigned short)(r >> 16);
}

// ---------------- fp32 -> bf16 convert (x4 vectorized) ----------------
__global__ __launch_bounds__(256) void k_cvt(const float* __restrict__ in,
                                             unsigned short* __restrict__ out, int n4) {
  int i = blockIdx.x * 256 + threadIdx.x;
  if (i >= n4) return;
  f32x4 v = reinterpret_cast<const f32x4*>(in)[i];
  u16x4 o;
  o[0] = f2bf(v[0]); o[1] = f2bf(v[1]); o[2] = f2bf(v[2]); o[3] = f2bf(v[3]);
  reinterpret_cast<u16x4*>(out)[i] = o;
}

// ---------------- RoPE cos/sin tables: (256, 64) ----------------
__global__ void k_tables(float* __restrict__ cosT, float* __restrict__ sinT) {
  int n = threadIdx.x;
  int r = n >> 4, cc = n & 15;
  for (int d = 0; d < 64; ++d) {
    int tpos = (d < 32) ? r : cc;
    int j = (d & 31) >> 1;
    float ang = (float)tpos * powf(10000.0f, -(float)j * (1.0f / 16.0f));
    cosT[n * 64 + d] = cosf(ang);
    sinT[n * 64 + d] = sinf(ang);
  }
}

// ---------------- 128x128x(BK=32) bf16 MFMA GEMM, B^T input ----------------
// m97 structure: global_load_lds width-16 staging into LINEAR LDS (no pad).
// EPI==0: qkv output -> RoPE(q,k)+scale(q), scatter to q/k (B,H,N,D) and vT (B,H,D,N)
// EPI==1: proj output -> +bias, fp32 to d_out
template <int EPI>
__global__ __launch_bounds__(256) void k_gemm(
    const unsigned short* __restrict__ A,  // M x K bf16
    const unsigned short* __restrict__ B,  // N x K bf16 (B^T layout)
    int M, int N, int K, int nTM,
    const float* __restrict__ cosT, const float* __restrict__ sinT,
    unsigned short* __restrict__ qout, unsigned short* __restrict__ kout,
    unsigned short* __restrict__ vTout,
    const float* __restrict__ bias, float* __restrict__ fout) {
  constexpr int LDT = 32;  // linear: global_load_lds dest is wave-uniform base + lane*16
  __shared__ unsigned short Al[128 * LDT];
  __shared__ unsigned short Bl[128 * LDT];
  const int tm = blockIdx.x % nTM, tn = blockIdx.x / nTM;
  const int m0 = tm * 128, n0 = tn * 128;
  const int t = threadIdx.x, w = t >> 6, l = t & 63, c = l & 15, g = l >> 4;
  const int wm = w >> 1, wn = w & 1;

  f32x4 acc[4][4];
#pragma unroll
  for (int i = 0; i < 4; ++i)
#pragma unroll
    for (int j = 0; j < 4; ++j) acc[i][j] = 0.0f;

  // staging geometry: 16B chunk per lane; 4 chunks per 64B row; 2 rounds cover 128 rows
  const int rr = t >> 2;           // row within 64-row half
  const int cc8 = (t & 3) * 8;     // element col within BK
  const unsigned short* Abase = A + (size_t)(m0 + rr) * K + cc8;
  const unsigned short* Bbase = B + (size_t)(n0 + rr) * K + cc8;
  const size_t rowSkip = (size_t)64 * K;  // second half-tile

  for (int kt = 0; kt < K; kt += 32) {
#pragma unroll
    for (int i = 0; i < 2; ++i) {
      __builtin_amdgcn_global_load_lds((glb_u16*)(Abase + i * rowSkip + kt),
                                       (lds_u16*)&Al[(i * 256 + w * 64) * 8], 16, 0, 0);
      __builtin_amdgcn_global_load_lds((glb_u16*)(Bbase + i * rowSkip + kt),
                                       (lds_u16*)&Bl[(i * 256 + w * 64) * 8], 16, 0, 0);
    }
    __syncthreads();
    bf16x8 af[4], bfr[4];
#pragma unroll
    for (int mf = 0; mf < 4; ++mf)
      af[mf] = *reinterpret_cast<const bf16x8*>(&Al[(wm * 64 + mf * 16 + c) * LDT + g * 8]);
#pragma unroll
    for (int nf = 0; nf < 4; ++nf)
      bfr[nf] = *reinterpret_cast<const bf16x8*>(&Bl[(wn * 64 + nf * 16 + c) * LDT + g * 8]);
#pragma unroll
    for (int mf = 0; mf < 4; ++mf)
#pragma unroll
      for (int nf = 0; nf < 4; ++nf)
        acc[mf][nf] = __builtin_amdgcn_mfma_f32_16x16x32_bf16(af[mf], bfr[nf], acc[mf][nf], 0, 0, 0);
    __syncthreads();
  }

  if constexpr (EPI == 0) {
    const int which = n0 >> 10;  // 0=q 1=k 2=v (uniform per block: 1024 % 128 == 0)
    unsigned short* qk = (which == 0) ? qout : kout;
#pragma unroll
    for (int nf = 0; nf < 4; ++nf) {
      const int o = n0 + wn * 64 + nf * 16 + c;
      const int h = (o >> 6) & 15;
      const int d = o & 63;
      if (which < 2) {
        const float sgn = (d & 1) ? 1.0f : -1.0f;
        const float qscale = (which == 0) ? 0.125f : 1.0f;  // fold D^-0.5 into q
#pragma unroll
        for (int mf = 0; mf < 4; ++mf) {
          const int m = m0 + wm * 64 + mf * 16 + g * 4;
          const int bb = m >> 8;
          const int nb = m & 255;
          f32x4 v = acc[mf][nf];
          f32x4 p;
          p[0] = __shfl_xor(v[0], 1);
          p[1] = __shfl_xor(v[1], 1);
          p[2] = __shfl_xor(v[2], 1);
          p[3] = __shfl_xor(v[3], 1);
          size_t base = ((size_t)(bb * 16 + h) * 256 + nb) * 64 + d;
#pragma unroll
          for (int j = 0; j < 4; ++j) {
            const int n = nb + j;
            const float cv = cosT[n * 64 + d];
            const float sv = sinT[n * 64 + d];
            float ov = (v[j] * cv + sgn * p[j] * sv) * qscale;
            qk[base + (size_t)j * 64] = f2bf(ov);
          }
        }
      } else {
#pragma unroll
        for (int mf = 0; mf < 4; ++mf) {
          const int m = m0 + wm * 64 + mf * 16 + g * 4;
          const int bb = m >> 8;
          const int nb = m & 255;
          f32x4 v = acc[mf][nf];
          u16x4 pk;
          pk[0] = f2bf(v[0]); pk[1] = f2bf(v[1]); pk[2] = f2bf(v[2]); pk[3] = f2bf(v[3]);
          size_t idx = ((size_t)(bb * 16 + h) * 64 + d) * 256 + nb;  // vT[b,h,d,n]
          *reinterpret_cast<u16x4*>(vTout + idx) = pk;
        }
      }
    }
  } else {
#pragma unroll
    for (int nf = 0; nf < 4; ++nf) {
      const int o = n0 + wn * 64 + nf * 16 + c;
      const float bv = bias[o];
#pragma unroll
      for (int mf = 0; mf < 4; ++mf) {
        const int m = m0 + wm * 64 + mf * 16 + g * 4;
        f32x4 v = acc[mf][nf];
#pragma unroll
        for (int j = 0; j < 4; ++j) fout[(size_t)(m + j) * N + o] = v[j] + bv;
      }
    }
  }
}

// ---------------- flash attention, swapped operands ----------------
__global__ __launch_bounds__(256) void k_attn(const unsigned short* __restrict__ Q,
                                              const unsigned short* __restrict__ Kb,
                                              const unsigned short* __restrict__ VT,
                                              unsigned short* __restrict__ Out) {
  constexpr int LDK = 80, LDP = 80;
  __shared__ unsigned short klds[64 * LDK];
  __shared__ unsigned short plds[4][64 * LDP];
  const int bh = blockIdx.x;
  const int bb = bh >> 4, h = bh & 15;
  const int t = threadIdx.x, w = t >> 6, l = t & 63, c = l & 15, g = l >> 4;
  const unsigned short* qh = Q + (size_t)bh * 256 * 64;
  const unsigned short* kh = Kb + (size_t)bh * 256 * 64;
  const unsigned short* vh = VT + (size_t)bh * 64 * 256;
  const int q0 = w * 64;

  bf16x8 qf[4][2];
#pragma unroll
  for (int nf = 0; nf < 4; ++nf)
#pragma unroll
    for (int ks = 0; ks < 2; ++ks)
      qf[nf][ks] = *reinterpret_cast<const bf16x8*>(qh + (q0 + nf * 16 + c) * 64 + ks * 32 + g * 8);

  f32x4 oacc[4][4];
#pragma unroll
  for (int i = 0; i < 4; ++i)
#pragma unroll
    for (int j = 0; j < 4; ++j) oacc[i][j] = 0.0f;
  float mr[4] = {-1e30f, -1e30f, -1e30f, -1e30f};
  float lr[4] = {0.f, 0.f, 0.f, 0.f};

  for (int ch = 0; ch < 4; ++ch) {
    __syncthreads();
    {
      int row = t >> 3, col = (t & 7) * 8;
#pragma unroll
      for (int rep = 0; rep < 2; ++rep) {
        int r = rep * 32 + row;
        bf16x8 kv = *reinterpret_cast<const bf16x8*>(kh + (ch * 64 + r) * 64 + col);
        *reinterpret_cast<bf16x8*>(&klds[r * LDK + col]) = kv;
      }
    }
    __syncthreads();

    f32x4 s[4][4];
#pragma unroll
    for (int i = 0; i < 4; ++i)
#pragma unroll
      for (int j = 0; j < 4; ++j) s[i][j] = 0.0f;
#pragma unroll
    for (int ks = 0; ks < 2; ++ks) {
      bf16x8 kf[4];
#pragma unroll
      for (int mf = 0; mf < 4; ++mf)
        kf[mf] = *reinterpret_cast<const bf16x8*>(&klds[(mf * 16 + c) * LDK + ks * 32 + g * 8]);
#pragma unroll
      for (int mf = 0; mf < 4; ++mf)
#pragma unroll
        for (int nf = 0; nf < 4; ++nf)
          s[mf][nf] = __builtin_amdgcn_mfma_f32_16x16x32_bf16(kf[mf], qf[nf][ks], s[mf][nf], 0, 0, 0);
    }

#pragma unroll
    for (int nf = 0; nf < 4; ++nf) {
      float mx = -1e30f;
#pragma unroll
      for (int mf = 0; mf < 4; ++mf)
#pragma unroll
        for (int j = 0; j < 4; ++j) mx = fmaxf(mx, s[mf][nf][j]);
      mx = fmaxf(mx, __shfl_xor(mx, 16));
      mx = fmaxf(mx, __shfl_xor(mx, 32));
      float mnew = fmaxf(mr[nf], mx);
      float rsc = __expf(mr[nf] - mnew);
      mr[nf] = mnew;
      float sum = 0.f;
#pragma unroll
      for (int mf = 0; mf < 4; ++mf)
#pragma unroll
        for (int j = 0; j < 4; ++j) {
          float p = __expf(s[mf][nf][j] - mnew);
          s[mf][nf][j] = p;
          sum += p;
        }
      sum += __shfl_xor(sum, 16);
      sum += __shfl_xor(sum, 32);
      lr[nf] = lr[nf] * rsc + sum;
#pragma unroll
      for (int mf = 0; mf < 4; ++mf) oacc[mf][nf] *= rsc;
    }

#pragma unroll
    for (int mf = 0; mf < 4; ++mf)
#pragma unroll
      for (int nf = 0; nf < 4; ++nf) {
        bf16x4 pk;
        pk[0] = (short)f2bf(s[mf][nf][0]);
        pk[1] = (short)f2bf(s[mf][nf][1]);
        pk[2] = (short)f2bf(s[mf][nf][2]);
        pk[3] = (short)f2bf(s[mf][nf][3]);
        *reinterpret_cast<bf16x4*>(&plds[w][(nf * 16 + c) * LDP + mf * 16 + g * 4]) = pk;
      }

#pragma unroll
    for (int ks = 0; ks < 2; ++ks) {
      bf16x8 vf[4], pf[4];
#pragma unroll
      for (int mf = 0; mf < 4; ++mf)
        vf[mf] = *reinterpret_cast<const bf16x8*>(vh + (mf * 16 + c) * 256 + ch * 64 + ks * 32 + g * 8);
#pragma unroll
      for (int nf = 0; nf < 4; ++nf) {
        bf16x4 p0 = *reinterpret_cast<const bf16x4*>(&plds[w][(nf * 16 + c) * LDP + ks * 32 + g * 8]);
        bf16x4 p1 = *reinterpret_cast<const bf16x4*>(&plds[w][(nf * 16 + c) * LDP + ks * 32 + g * 8 + 4]);
        pf[nf] = __builtin_shufflevector(p0, p1, 0, 1, 2, 3, 4, 5, 6, 7);
      }
#pragma unroll
      for (int mf = 0; mf < 4; ++mf)
#pragma unroll
        for (int nf = 0; nf < 4; ++nf)
          oacc[mf][nf] = __builtin_amdgcn_mfma_f32_16x16x32_bf16(vf[mf], pf[nf], oacc[mf][nf], 0, 0, 0);
    }
  }

  float linv[4];
#pragma unroll
  for (int nf = 0; nf < 4; ++nf) linv[nf] = 1.0f / lr[nf];
#pragma unroll
  for (int mf = 0; mf < 4; ++mf)
#pragma unroll
    for (int nf = 0; nf < 4; ++nf) {
      f32x4 v = oacc[mf][nf];
      u16x4 pk;
      pk[0] = f2bf(v[0] * linv[nf]);
      pk[1] = f2bf(v[1] * linv[nf]);
      pk[2] = f2bf(v[2] * linv[nf]);
      pk[3] = f2bf(v[3] * linv[nf]);
      size_t row = (size_t)bb * 256 + q0 + nf * 16 + c;
      size_t idx = row * 1024 + (size_t)h * 64 + mf * 16 + g * 4;  // out[b,n, h*64+d]
      *reinterpret_cast<u16x4*>(Out + idx) = pk;
    }
}

extern "C" void kernel_launch(void* const* d_in, const int* in_sizes, int n_in,
                              void* d_out, int out_size, void* d_ws, size_t ws_size,
                              hipStream_t stream) {
  const float* x = (const float*)d_in[0];
  const float* wqkv = (const float*)d_in[1];
  const float* wproj = (const float*)d_in[2];
  const float* bproj = (const float*)d_in[3];

  char* ws = (char*)d_ws;
  unsigned short* xb = (unsigned short*)(ws);                 // 33,554,432 B (reused as attn_out)
  unsigned short* wqkvb = (unsigned short*)(ws + 33554432);   //  6,291,456 B
  unsigned short* wprojb = (unsigned short*)(ws + 39845888);  //  2,097,152 B
  float* cosT = (float*)(ws + 41943040);                      //     65,536 B
  float* sinT = (float*)(ws + 42008576);                      //     65,536 B
  unsigned short* qb = (unsigned short*)(ws + 42074112);      // 33,554,432 B
  unsigned short* kb = (unsigned short*)(ws + 75628544);      // 33,554,432 B
  unsigned short* vtb = (unsigned short*)(ws + 109182976);    // 33,554,432 B -> total 142,737,408 B
  unsigned short* attn_out = xb;

  k_cvt<<<16384, 256, 0, stream>>>(x, xb, 4194304);
  k_cvt<<<3072, 256, 0, stream>>>(wqkv, wqkvb, 786432);
  k_cvt<<<1024, 256, 0, stream>>>(wproj, wprojb, 262144);
  k_tables<<<1, 256, 0, stream>>>(cosT, sinT);

  // QKV: M=16384, N=3072, K=1024 (B^T layout), RoPE epilogue
  k_gemm<0><<<128 * 24, 256, 0, stream>>>(xb, wqkvb, 16384, 3072, 1024, 128,
                                          cosT, sinT, qb, kb, vtb, nullptr, nullptr);
  // attention: one block per (b,h)
  k_attn<<<1024, 256, 0, stream>>>(qb, kb, vtb, attn_out);
  // proj: M=16384, N=1024, K=1024, +bias, fp32 out
  k_gemm<1><<<128 * 8, 256, 0, stream>>>(attn_out, wprojb, 16384, 1024, 1024, 128,
                                         nullptr, nullptr, nullptr, nullptr, nullptr,
                                         bproj, (float*)d_out);
}

// Round 4
// 302.399 us; speedup vs baseline: 1.1949x; 1.1502x over previous
//
#include <hip/hip_runtime.h>
#include <stdint.h>

typedef __attribute__((ext_vector_type(8))) short bf16x8;
typedef __attribute__((ext_vector_type(4))) short bf16x4;
typedef __attribute__((ext_vector_type(4))) float f32x4;
typedef __attribute__((ext_vector_type(4))) unsigned short u16x4;

typedef __attribute__((address_space(3))) unsigned short lds_u16;
typedef const __attribute__((address_space(1))) unsigned short glb_u16;

__device__ __forceinline__ unsigned short f2bf(float f) {
  union { float f; unsigned u; } x; x.f = f;
  unsigned r = x.u + 0x7FFFu + ((x.u >> 16) & 1u);
  return (unsigned short)(r >> 16);
}

// ---------------- fp32 -> bf16 convert (x4 vectorized) ----------------
__global__ __launch_bounds__(256) void k_cvt(const float* __restrict__ in,
                                             unsigned short* __restrict__ out, int n4) {
  int i = blockIdx.x * 256 + threadIdx.x;
  if (i >= n4) return;
  f32x4 v = reinterpret_cast<const f32x4*>(in)[i];
  u16x4 o;
  o[0] = f2bf(v[0]); o[1] = f2bf(v[1]); o[2] = f2bf(v[2]); o[3] = f2bf(v[3]);
  reinterpret_cast<u16x4*>(out)[i] = o;
}

// ---------------- RoPE cos/sin tables: (256, 64) ----------------
__global__ void k_tables(float* __restrict__ cosT, float* __restrict__ sinT) {
  int n = threadIdx.x;
  int r = n >> 4, cc = n & 15;
  for (int d = 0; d < 64; ++d) {
    int tpos = (d < 32) ? r : cc;
    int j = (d & 31) >> 1;
    float ang = (float)tpos * powf(10000.0f, -(float)j * (1.0f / 16.0f));
    cosT[n * 64 + d] = cosf(ang);
    sinT[n * 64 + d] = sinf(ang);
  }
}

// ============ 256x256xBK64, 8-wave (2x4), phase-interleaved MFMA GEMM ============
// LDS 128 KiB: A[2dbuf][256][64], B[2dbuf][256][64] bf16, st_16x32 XOR-swizzled
// (byte ^= ((byte>>9)&1)<<5, applied via pre-swizzled global source + swizzled ds_read).
// Per K-tile: 4 phases x 16 MFMA; stages for K-tile k+2 issued only after the target
// region's reads completed (lgkm(0) before each raw s_barrier); vmcnt(8)+barrier at
// K-tile boundaries keeps 8 loads (1 K-tile) in flight. No __syncthreads in main loop.
template <int EPI>
__global__ __launch_bounds__(512, 2) void k_gemm(
    const unsigned short* __restrict__ A,  // M x K bf16
    const unsigned short* __restrict__ B,  // N x K bf16 (B^T layout)
    int M, int N, int K, int nTM,
    const float* __restrict__ cosT, const float* __restrict__ sinT,
    unsigned short* __restrict__ qout, unsigned short* __restrict__ kout,
    unsigned short* __restrict__ vTout,
    const float* __restrict__ bias, float* __restrict__ fout) {
  __shared__ unsigned short smem_u16[65536];  // 128 KiB

  const int t = threadIdx.x, w = t >> 6, l = t & 63, c = l & 15, g = l >> 4;
  const int wm = w >> 2, wn = w & 3;

  // XCD-aware bijective swizzle (grid % 8 == 0 for both call sites)
  const int nwg = gridDim.x;
  const int bid = (int)blockIdx.x;
  const int swz = (bid & 7) * (nwg >> 3) + (bid >> 3);
  const int tm = swz % nTM, tn = swz / nTM;
  const int m0 = tm * 256, n0 = tn * 256;

  // ---- stage source (pre-swizzled): thread t covers one 16B chunk of an 8192B issue
  const int rS = t >> 3;                                   // row 0..63 within chunk
  const int colS = ((t & 7) * 8) ^ (((t >> 5) & 1) << 4);  // element col, swizzled
  const unsigned short* Asrc = A + (size_t)(m0 + rS) * K + colS;
  const unsigned short* Bsrc = B + (size_t)(n0 + rS) * K + colS;
  const size_t hK = (size_t)128 * K;  // half-tile row skip
  const size_t iK = (size_t)64 * K;   // chunk row skip

#define STG_A(db, half, i, kt)                                                              \
  __builtin_amdgcn_global_load_lds((glb_u16*)(Asrc + (half) * hK + (i) * iK + (kt) * 64),   \
      (lds_u16*)&smem_u16[((db) * 32768 + (half) * 16384 + (i) * 8192 + w * 1024) >> 1],    \
      16, 0, 0)
#define STG_B(db, half, i, kt)                                                                      \
  __builtin_amdgcn_global_load_lds((glb_u16*)(Bsrc + (half) * hK + (i) * iK + (kt) * 64),           \
      (lds_u16*)&smem_u16[(65536 + (db) * 32768 + (half) * 16384 + (i) * 8192 + w * 1024) >> 1],    \
      16, 0, 0)

  // prologue: stage K-tiles 0 (buf0) and 1 (buf1) = 16 loads/wave
#pragma unroll
  for (int kk = 0; kk < 2; ++kk) {
    STG_A(kk, 0, 0, kk); STG_A(kk, 0, 1, kk); STG_A(kk, 1, 0, kk); STG_A(kk, 1, 1, kk);
    STG_B(kk, 0, 0, kk); STG_B(kk, 0, 1, kk); STG_B(kk, 1, 0, kk); STG_B(kk, 1, 1, kk);
  }

  f32x4 acc[8][4];
#pragma unroll
  for (int i = 0; i < 8; ++i)
#pragma unroll
    for (int j = 0; j < 4; ++j) acc[i][j] = 0.0f;

  // ---- fragment read addressing (swizzled): flip bit5 of k-offset when (row>>2)&1
  const int xm = ((c >> 2) & 1) << 5;
  const int ko0 = (g * 16) ^ xm;  // ks=0 byte offset within 128B row
  const int ko1 = ko0 + 64;       // ks=1 (bit6 unaffected by xm)
  const int rAb = (wm * 128 + c) * 128;  // byte row base (+ mf*2048)
  const int rBb = (wn * 64 + c) * 128;   // byte row base (+ nf*2048)

  asm volatile("s_waitcnt vmcnt(8)" ::: "memory");
  __builtin_amdgcn_s_barrier();
  asm volatile("" ::: "memory");

  const int nKT = K >> 6;
  for (int k = 0; k < nKT; ++k) {
    const int db = k & 1;
    const int Abo = db * 32768;
    const int Bbo = 65536 + db * 32768;
    const int k2 = k + 2;
    const bool st = (k2 < nKT);

    bf16x8 a0[4][2], a1[4][2], bq[4][2];
    // ================= P1: read A(mf0-3)+B(all); MFMA mf0-3 x nf0-1 =================
#pragma unroll
    for (int mf = 0; mf < 4; ++mf) {
      a0[mf][0] = *(const bf16x8*)&smem_u16[(Abo + rAb + mf * 2048 + ko0) >> 1];
      a0[mf][1] = *(const bf16x8*)&smem_u16[(Abo + rAb + mf * 2048 + ko1) >> 1];
    }
#pragma unroll
    for (int nf = 0; nf < 4; ++nf) {
      bq[nf][0] = *(const bf16x8*)&smem_u16[(Bbo + rBb + nf * 2048 + ko0) >> 1];
      bq[nf][1] = *(const bf16x8*)&smem_u16[(Bbo + rBb + nf * 2048 + ko1) >> 1];
    }
    asm volatile("s_waitcnt lgkmcnt(0)" ::: "memory");
    __builtin_amdgcn_s_setprio(1);
#pragma unroll
    for (int mf = 0; mf < 4; ++mf)
#pragma unroll
      for (int nf = 0; nf < 2; ++nf)
#pragma unroll
        for (int ks = 0; ks < 2; ++ks)
          acc[mf][nf] = __builtin_amdgcn_mfma_f32_16x16x32_bf16(a0[mf][ks], bq[nf][ks], acc[mf][nf], 0, 0, 0);
    __builtin_amdgcn_s_setprio(0);
    __builtin_amdgcn_sched_barrier(0);
    __builtin_amdgcn_s_barrier();
    asm volatile("" ::: "memory");

    // ====== P2: stage A-i0 chunks + B00 (regions read-complete); read A(mf4-7); MFMA mf0-3 x nf2-3 ======
    if (st) { STG_A(db, 0, 0, k2); STG_A(db, 1, 0, k2); STG_B(db, 0, 0, k2); }
#pragma unroll
    for (int mf = 0; mf < 4; ++mf) {
      a1[mf][0] = *(const bf16x8*)&smem_u16[(Abo + rAb + (mf + 4) * 2048 + ko0) >> 1];
      a1[mf][1] = *(const bf16x8*)&smem_u16[(Abo + rAb + (mf + 4) * 2048 + ko1) >> 1];
    }
    asm volatile("s_waitcnt lgkmcnt(0)" ::: "memory");
    __builtin_amdgcn_s_setprio(1);
#pragma unroll
    for (int mf = 0; mf < 4; ++mf)
#pragma unroll
      for (int nf = 2; nf < 4; ++nf)
#pragma unroll
        for (int ks = 0; ks < 2; ++ks)
          acc[mf][nf] = __builtin_amdgcn_mfma_f32_16x16x32_bf16(a0[mf][ks], bq[nf][ks], acc[mf][nf], 0, 0, 0);
    __builtin_amdgcn_s_setprio(0);
    __builtin_amdgcn_sched_barrier(0);
    __builtin_amdgcn_s_barrier();
    asm volatile("" ::: "memory");

    // ====== P3: stage A-i1 chunks + B01; MFMA mf4-7 x nf0-1 ======
    if (st) { STG_A(db, 0, 1, k2); STG_A(db, 1, 1, k2); STG_B(db, 0, 1, k2); }
    __builtin_amdgcn_s_setprio(1);
#pragma unroll
    for (int mf = 0; mf < 4; ++mf)
#pragma unroll
      for (int nf = 0; nf < 2; ++nf)
#pragma unroll
        for (int ks = 0; ks < 2; ++ks)
          acc[mf + 4][nf] = __builtin_amdgcn_mfma_f32_16x16x32_bf16(a1[mf][ks], bq[nf][ks], acc[mf + 4][nf], 0, 0, 0);
    __builtin_amdgcn_s_setprio(0);
    __builtin_amdgcn_sched_barrier(0);
    __builtin_amdgcn_s_barrier();
    asm volatile("" ::: "memory");

    // ====== P4: stage B-h1 chunks; MFMA mf4-7 x nf2-3; boundary vmcnt+barrier ======
    if (st) { STG_B(db, 1, 0, k2); STG_B(db, 1, 1, k2); }
    __builtin_amdgcn_s_setprio(1);
#pragma unroll
    for (int mf = 0; mf < 4; ++mf)
#pragma unroll
      for (int nf = 2; nf < 4; ++nf)
#pragma unroll
        for (int ks = 0; ks < 2; ++ks)
          acc[mf + 4][nf] = __builtin_amdgcn_mfma_f32_16x16x32_bf16(a1[mf][ks], bq[nf][ks], acc[mf + 4][nf], 0, 0, 0);
    __builtin_amdgcn_s_setprio(0);
    __builtin_amdgcn_sched_barrier(0);
    if (k < nKT - 2) {
      asm volatile("s_waitcnt vmcnt(8)" ::: "memory");
      __builtin_amdgcn_s_barrier();
      asm volatile("" ::: "memory");
    } else if (k == nKT - 2) {
      asm volatile("s_waitcnt vmcnt(0)" ::: "memory");
      __builtin_amdgcn_s_barrier();
      asm volatile("" ::: "memory");
    }
  }
#undef STG_A
#undef STG_B

  if constexpr (EPI == 0) {
    const int which = n0 >> 10;  // 0=q 1=k 2=v (uniform: 1024 % 256 == 0)
    unsigned short* qk = (which == 0) ? qout : kout;
#pragma unroll
    for (int nf = 0; nf < 4; ++nf) {
      const int o = n0 + wn * 64 + nf * 16 + c;
      const int h = (o >> 6) & 15;
      const int d = o & 63;
      if (which < 2) {
        const float sgn = (d & 1) ? 1.0f : -1.0f;
        const float qscale = (which == 0) ? 0.125f : 1.0f;  // fold D^-0.5 into q
#pragma unroll
        for (int mf = 0; mf < 8; ++mf) {
          const int m = m0 + wm * 128 + mf * 16 + g * 4;
          const int bb = m >> 8;
          const int nb = m & 255;
          f32x4 v = acc[mf][nf];
          f32x4 p;
          p[0] = __shfl_xor(v[0], 1);
          p[1] = __shfl_xor(v[1], 1);
          p[2] = __shfl_xor(v[2], 1);
          p[3] = __shfl_xor(v[3], 1);
          size_t base = ((size_t)(bb * 16 + h) * 256 + nb) * 64 + d;
#pragma unroll
          for (int j = 0; j < 4; ++j) {
            const int n = nb + j;
            const float cv = cosT[n * 64 + d];
            const float sv = sinT[n * 64 + d];
            float ov = (v[j] * cv + sgn * p[j] * sv) * qscale;
            qk[base + (size_t)j * 64] = f2bf(ov);
          }
        }
      } else {
#pragma unroll
        for (int mf = 0; mf < 8; ++mf) {
          const int m = m0 + wm * 128 + mf * 16 + g * 4;
          const int bb = m >> 8;
          const int nb = m & 255;
          f32x4 v = acc[mf][nf];
          u16x4 pk;
          pk[0] = f2bf(v[0]); pk[1] = f2bf(v[1]); pk[2] = f2bf(v[2]); pk[3] = f2bf(v[3]);
          size_t idx = ((size_t)(bb * 16 + h) * 64 + d) * 256 + nb;  // vT[b,h,d,n]
          *reinterpret_cast<u16x4*>(vTout + idx) = pk;
        }
      }
    }
  } else {
#pragma unroll
    for (int nf = 0; nf < 4; ++nf) {
      const int o = n0 + wn * 64 + nf * 16 + c;
      const float bv = bias[o];
#pragma unroll
      for (int mf = 0; mf < 8; ++mf) {
        const int m = m0 + wm * 128 + mf * 16 + g * 4;
        f32x4 v = acc[mf][nf];
#pragma unroll
        for (int j = 0; j < 4; ++j) fout[(size_t)(m + j) * N + o] = v[j] + bv;
      }
    }
  }
}

// ---------------- flash attention, swapped operands (unchanged) ----------------
__global__ __launch_bounds__(256) void k_attn(const unsigned short* __restrict__ Q,
                                              const unsigned short* __restrict__ Kb,
                                              const unsigned short* __restrict__ VT,
                                              unsigned short* __restrict__ Out) {
  constexpr int LDK = 80, LDP = 80;
  __shared__ unsigned short klds[64 * LDK];
  __shared__ unsigned short plds[4][64 * LDP];
  const int bh = blockIdx.x;
  const int bb = bh >> 4, h = bh & 15;
  const int t = threadIdx.x, w = t >> 6, l = t & 63, c = l & 15, g = l >> 4;
  const unsigned short* qh = Q + (size_t)bh * 256 * 64;
  const unsigned short* kh = Kb + (size_t)bh * 256 * 64;
  const unsigned short* vh = VT + (size_t)bh * 64 * 256;
  const int q0 = w * 64;

  bf16x8 qf[4][2];
#pragma unroll
  for (int nf = 0; nf < 4; ++nf)
#pragma unroll
    for (int ks = 0; ks < 2; ++ks)
      qf[nf][ks] = *reinterpret_cast<const bf16x8*>(qh + (q0 + nf * 16 + c) * 64 + ks * 32 + g * 8);

  f32x4 oacc[4][4];
#pragma unroll
  for (int i = 0; i < 4; ++i)
#pragma unroll
    for (int j = 0; j < 4; ++j) oacc[i][j] = 0.0f;
  float mr[4] = {-1e30f, -1e30f, -1e30f, -1e30f};
  float lr[4] = {0.f, 0.f, 0.f, 0.f};

  for (int ch = 0; ch < 4; ++ch) {
    __syncthreads();
    {
      int row = t >> 3, col = (t & 7) * 8;
#pragma unroll
      for (int rep = 0; rep < 2; ++rep) {
        int r = rep * 32 + row;
        bf16x8 kv = *reinterpret_cast<const bf16x8*>(kh + (ch * 64 + r) * 64 + col);
        *reinterpret_cast<bf16x8*>(&klds[r * LDK + col]) = kv;
      }
    }
    __syncthreads();

    f32x4 s[4][4];
#pragma unroll
    for (int i = 0; i < 4; ++i)
#pragma unroll
      for (int j = 0; j < 4; ++j) s[i][j] = 0.0f;
#pragma unroll
    for (int ks = 0; ks < 2; ++ks) {
      bf16x8 kf[4];
#pragma unroll
      for (int mf = 0; mf < 4; ++mf)
        kf[mf] = *reinterpret_cast<const bf16x8*>(&klds[(mf * 16 + c) * LDK + ks * 32 + g * 8]);
#pragma unroll
      for (int mf = 0; mf < 4; ++mf)
#pragma unroll
        for (int nf = 0; nf < 4; ++nf)
          s[mf][nf] = __builtin_amdgcn_mfma_f32_16x16x32_bf16(kf[mf], qf[nf][ks], s[mf][nf], 0, 0, 0);
    }

#pragma unroll
    for (int nf = 0; nf < 4; ++nf) {
      float mx = -1e30f;
#pragma unroll
      for (int mf = 0; mf < 4; ++mf)
#pragma unroll
        for (int j = 0; j < 4; ++j) mx = fmaxf(mx, s[mf][nf][j]);
      mx = fmaxf(mx, __shfl_xor(mx, 16));
      mx = fmaxf(mx, __shfl_xor(mx, 32));
      float mnew = fmaxf(mr[nf], mx);
      float rsc = __expf(mr[nf] - mnew);
      mr[nf] = mnew;
      float sum = 0.f;
#pragma unroll
      for (int mf = 0; mf < 4; ++mf)
#pragma unroll
        for (int j = 0; j < 4; ++j) {
          float p = __expf(s[mf][nf][j] - mnew);
          s[mf][nf][j] = p;
          sum += p;
        }
      sum += __shfl_xor(sum, 16);
      sum += __shfl_xor(sum, 32);
      lr[nf] = lr[nf] * rsc + sum;
#pragma unroll
      for (int mf = 0; mf < 4; ++mf) oacc[mf][nf] *= rsc;
    }

#pragma unroll
    for (int mf = 0; mf < 4; ++mf)
#pragma unroll
      for (int nf = 0; nf < 4; ++nf) {
        bf16x4 pk;
        pk[0] = (short)f2bf(s[mf][nf][0]);
        pk[1] = (short)f2bf(s[mf][nf][1]);
        pk[2] = (short)f2bf(s[mf][nf][2]);
        pk[3] = (short)f2bf(s[mf][nf][3]);
        *reinterpret_cast<bf16x4*>(&plds[w][(nf * 16 + c) * LDP + mf * 16 + g * 4]) = pk;
      }

#pragma unroll
    for (int ks = 0; ks < 2; ++ks) {
      bf16x8 vf[4], pf[4];
#pragma unroll
      for (int mf = 0; mf < 4; ++mf)
        vf[mf] = *reinterpret_cast<const bf16x8*>(vh + (mf * 16 + c) * 256 + ch * 64 + ks * 32 + g * 8);
#pragma unroll
      for (int nf = 0; nf < 4; ++nf) {
        bf16x4 p0 = *reinterpret_cast<const bf16x4*>(&plds[w][(nf * 16 + c) * LDP + ks * 32 + g * 8]);
        bf16x4 p1 = *reinterpret_cast<const bf16x4*>(&plds[w][(nf * 16 + c) * LDP + ks * 32 + g * 8 + 4]);
        pf[nf] = __builtin_shufflevector(p0, p1, 0, 1, 2, 3, 4, 5, 6, 7);
      }
#pragma unroll
      for (int mf = 0; mf < 4; ++mf)
#pragma unroll
        for (int nf = 0; nf < 4; ++nf)
          oacc[mf][nf] = __builtin_amdgcn_mfma_f32_16x16x32_bf16(vf[mf], pf[nf], oacc[mf][nf], 0, 0, 0);
    }
  }

  float linv[4];
#pragma unroll
  for (int nf = 0; nf < 4; ++nf) linv[nf] = 1.0f / lr[nf];
#pragma unroll
  for (int mf = 0; mf < 4; ++mf)
#pragma unroll
    for (int nf = 0; nf < 4; ++nf) {
      f32x4 v = oacc[mf][nf];
      u16x4 pk;
      pk[0] = f2bf(v[0] * linv[nf]);
      pk[1] = f2bf(v[1] * linv[nf]);
      pk[2] = f2bf(v[2] * linv[nf]);
      pk[3] = f2bf(v[3] * linv[nf]);
      size_t row = (size_t)bb * 256 + q0 + nf * 16 + c;
      size_t idx = row * 1024 + (size_t)h * 64 + mf * 16 + g * 4;  // out[b,n, h*64+d]
      *reinterpret_cast<u16x4*>(Out + idx) = pk;
    }
}

extern "C" void kernel_launch(void* const* d_in, const int* in_sizes, int n_in,
                              void* d_out, int out_size, void* d_ws, size_t ws_size,
                              hipStream_t stream) {
  const float* x = (const float*)d_in[0];
  const float* wqkv = (const float*)d_in[1];
  const float* wproj = (const float*)d_in[2];
  const float* bproj = (const float*)d_in[3];

  char* ws = (char*)d_ws;
  unsigned short* xb = (unsigned short*)(ws);                 // 33,554,432 B (reused as attn_out)
  unsigned short* wqkvb = (unsigned short*)(ws + 33554432);   //  6,291,456 B
  unsigned short* wprojb = (unsigned short*)(ws + 39845888);  //  2,097,152 B
  float* cosT = (float*)(ws + 41943040);                      //     65,536 B
  float* sinT = (float*)(ws + 42008576);                      //     65,536 B
  unsigned short* qb = (unsigned short*)(ws + 42074112);      // 33,554,432 B
  unsigned short* kb = (unsigned short*)(ws + 75628544);      // 33,554,432 B
  unsigned short* vtb = (unsigned short*)(ws + 109182976);    // 33,554,432 B -> total 142,737,408 B
  unsigned short* attn_out = xb;

  k_cvt<<<16384, 256, 0, stream>>>(x, xb, 4194304);
  k_cvt<<<3072, 256, 0, stream>>>(wqkv, wqkvb, 786432);
  k_cvt<<<1024, 256, 0, stream>>>(wproj, wprojb, 262144);
  k_tables<<<1, 256, 0, stream>>>(cosT, sinT);

  // QKV: M=16384 (64 tiles), N=3072 (12 tiles), K=1024; RoPE epilogue. grid=768 (%8==0)
  k_gemm<0><<<64 * 12, 512, 0, stream>>>(xb, wqkvb, 16384, 3072, 1024, 64,
                                         cosT, sinT, qb, kb, vtb, nullptr, nullptr);
  // attention: one block per (b,h)
  k_attn<<<1024, 256, 0, stream>>>(qb, kb, vtb, attn_out);
  // proj: M=16384 (64 tiles), N=1024 (4 tiles), K=1024, +bias, fp32 out. grid=256 (%8==0)
  k_gemm<1><<<64 * 4, 512, 0, stream>>>(attn_out, wprojb, 16384, 1024, 1024, 64,
                                        nullptr, nullptr, nullptr, nullptr, nullptr,
                                        bproj, (float*)d_out);
}

// Round 5
// 298.999 us; speedup vs baseline: 1.2085x; 1.0114x over previous
//
#include <hip/hip_runtime.h>
#include <stdint.h>

typedef __attribute__((ext_vector_type(8))) short bf16x8;
typedef __attribute__((ext_vector_type(4))) short bf16x4;
typedef __attribute__((ext_vector_type(4))) float f32x4;
typedef __attribute__((ext_vector_type(4))) unsigned short u16x4;

typedef __attribute__((address_space(3))) unsigned short lds_u16;
typedef const __attribute__((address_space(1))) unsigned short glb_u16;

__device__ __forceinline__ unsigned short f2bf(float f) {
  union { float f; unsigned u; } x; x.f = f;
  unsigned r = x.u + 0x7FFFu + ((x.u >> 16) & 1u);
  return (unsigned short)(r >> 16);
}

// ---------------- fp32 -> bf16 convert (x4 vectorized) ----------------
__global__ __launch_bounds__(256) void k_cvt(const float* __restrict__ in,
                                             unsigned short* __restrict__ out, int n4) {
  int i = blockIdx.x * 256 + threadIdx.x;
  if (i >= n4) return;
  f32x4 v = reinterpret_cast<const f32x4*>(in)[i];
  u16x4 o;
  o[0] = f2bf(v[0]); o[1] = f2bf(v[1]); o[2] = f2bf(v[2]); o[3] = f2bf(v[3]);
  reinterpret_cast<u16x4*>(out)[i] = o;
}

// ---------------- RoPE cos/sin tables: (256, 64) ----------------
__global__ void k_tables(float* __restrict__ cosT, float* __restrict__ sinT) {
  int n = threadIdx.x;
  int r = n >> 4, cc = n & 15;
  for (int d = 0; d < 64; ++d) {
    int tpos = (d < 32) ? r : cc;
    int j = (d & 31) >> 1;
    float ang = (float)tpos * powf(10000.0f, -(float)j * (1.0f / 16.0f));
    cosT[n * 64 + d] = cosf(ang);
    sinT[n * 64 + d] = sinf(ang);
  }
}

// ============ 256x256xBK64, 8-wave (2x4), phase-interleaved MFMA GEMM ============
// LDS 128 KiB, st_16x32 XOR-swizzle (pre-swizzled global src + swizzled ds_read).
// Schedule: P1 = all 24 ds_reads (lgkm(8) -> M1 overlaps a1 arrival; trailing lgkm(0)
// establishes stage-safety); P2/P3/P4 = {stage k+2 chunk(s) into read-complete regions;
// 16 reg-only MFMA}; boundary vmcnt(8) at P4 keeps one K-tile of loads in flight.
// Block mapping: per-XCD A-band (tm = xcd*nTM/8 + j/nTN), tn fastest -> A L2-resident.
template <int EPI>
__global__ __launch_bounds__(512, 2) void k_gemm(
    const unsigned short* __restrict__ A,  // M x K bf16
    const unsigned short* __restrict__ B,  // N x K bf16 (B^T layout)
    int M, int N, int K, int nTM,
    const float* __restrict__ cosT, const float* __restrict__ sinT,
    unsigned short* __restrict__ qout, unsigned short* __restrict__ kout,
    unsigned short* __restrict__ vTout,
    const float* __restrict__ bias, float* __restrict__ fout) {
  __shared__ unsigned short smem_u16[65536];  // 128 KiB

  const int t = threadIdx.x, w = t >> 6, l = t & 63, c = l & 15, g = l >> 4;
  const int wm = w >> 2, wn = w & 3;

  // L2-locality mapping: each XCD owns an A-band of nTM/8 row-tiles, tn fastest.
  const int nwg = gridDim.x;
  const int bid = (int)blockIdx.x;
  const int nTN = nwg / nTM;
  const int xcd = bid & 7;
  const int j = bid >> 3;
  const int tn = j % nTN;
  const int tm = xcd * (nTM >> 3) + j / nTN;
  const int m0 = tm * 256, n0 = tn * 256;

  // ---- stage source (pre-swizzled): thread t covers one 16B chunk of an 8192B issue
  const int rS = t >> 3;                                   // row 0..63 within chunk
  const int colS = ((t & 7) * 8) ^ (((t >> 5) & 1) << 4);  // element col, swizzled
  const unsigned short* Asrc = A + (size_t)(m0 + rS) * K + colS;
  const unsigned short* Bsrc = B + (size_t)(n0 + rS) * K + colS;
  const size_t hK = (size_t)128 * K;  // half-tile row skip
  const size_t iK = (size_t)64 * K;   // chunk row skip

#define STG_A(db, half, i, kt)                                                              \
  __builtin_amdgcn_global_load_lds((glb_u16*)(Asrc + (half) * hK + (i) * iK + (kt) * 64),   \
      (lds_u16*)&smem_u16[((db) * 32768 + (half) * 16384 + (i) * 8192 + w * 1024) >> 1],    \
      16, 0, 0)
#define STG_B(db, half, i, kt)                                                                      \
  __builtin_amdgcn_global_load_lds((glb_u16*)(Bsrc + (half) * hK + (i) * iK + (kt) * 64),           \
      (lds_u16*)&smem_u16[(65536 + (db) * 32768 + (half) * 16384 + (i) * 8192 + w * 1024) >> 1],    \
      16, 0, 0)

  // prologue: stage K-tiles 0 (buf0) and 1 (buf1) = 16 loads/wave
#pragma unroll
  for (int kk = 0; kk < 2; ++kk) {
    STG_A(kk, 0, 0, kk); STG_A(kk, 0, 1, kk); STG_A(kk, 1, 0, kk); STG_A(kk, 1, 1, kk);
    STG_B(kk, 0, 0, kk); STG_B(kk, 0, 1, kk); STG_B(kk, 1, 0, kk); STG_B(kk, 1, 1, kk);
  }

  f32x4 acc[8][4];
#pragma unroll
  for (int i = 0; i < 8; ++i)
#pragma unroll
    for (int jj = 0; jj < 4; ++jj) acc[i][jj] = 0.0f;

  // ---- fragment read addressing (swizzled): flip bit5 of k-offset when (row>>2)&1
  const int xm = ((c >> 2) & 1) << 5;
  const int ko0 = (g * 16) ^ xm;  // ks=0 byte offset within 128B row
  const int ko1 = ko0 + 64;       // ks=1 (bit6 unaffected by xm)
  const int rAb = (wm * 128 + c) * 128;  // byte row base (+ mf*2048)
  const int rBb = (wn * 64 + c) * 128;   // byte row base (+ nf*2048)

  asm volatile("s_waitcnt vmcnt(8)" ::: "memory");  // tile 0 landed; tile 1 in flight
  __builtin_amdgcn_s_barrier();
  asm volatile("" ::: "memory");

  bf16x8 a0[4][2], a1[4][2], bq[4][2];
  const int nKT = K >> 6;
  for (int k = 0; k < nKT; ++k) {
    const int db = k & 1;
    const int Abo = db * 32768;
    const int Bbo = 65536 + db * 32768;
    const int k2 = k + 2;
    const bool st = (k2 < nKT);

    // ============ P1: all 24 ds_reads; M1 overlaps a1 arrival ============
#pragma unroll
    for (int mf = 0; mf < 4; ++mf) {
      a0[mf][0] = *(const bf16x8*)&smem_u16[(Abo + rAb + mf * 2048 + ko0) >> 1];
      a0[mf][1] = *(const bf16x8*)&smem_u16[(Abo + rAb + mf * 2048 + ko1) >> 1];
    }
#pragma unroll
    for (int nf = 0; nf < 4; ++nf) {
      bq[nf][0] = *(const bf16x8*)&smem_u16[(Bbo + rBb + nf * 2048 + ko0) >> 1];
      bq[nf][1] = *(const bf16x8*)&smem_u16[(Bbo + rBb + nf * 2048 + ko1) >> 1];
    }
#pragma unroll
    for (int mf = 0; mf < 4; ++mf) {
      a1[mf][0] = *(const bf16x8*)&smem_u16[(Abo + rAb + (mf + 4) * 2048 + ko0) >> 1];
      a1[mf][1] = *(const bf16x8*)&smem_u16[(Abo + rAb + (mf + 4) * 2048 + ko1) >> 1];
    }
    asm volatile("s_waitcnt lgkmcnt(8)" ::: "memory");  // a0+bq arrived (a1 in flight)
    __builtin_amdgcn_sched_barrier(0);
    __builtin_amdgcn_s_setprio(1);
#pragma unroll
    for (int mf = 0; mf < 4; ++mf)
#pragma unroll
      for (int nf = 0; nf < 2; ++nf)
#pragma unroll
        for (int ks = 0; ks < 2; ++ks)
          acc[mf][nf] = __builtin_amdgcn_mfma_f32_16x16x32_bf16(a0[mf][ks], bq[nf][ks], acc[mf][nf], 0, 0, 0);
    __builtin_amdgcn_s_setprio(0);
    asm volatile("s_waitcnt lgkmcnt(0)" ::: "memory");  // a1 drained -> stage-safety for P3
    __builtin_amdgcn_sched_barrier(0);
    __builtin_amdgcn_s_barrier();
    asm volatile("" ::: "memory");

    // ============ P2: stage A00,A10,B00 (read-complete at P1 end); M2 reg-only ============
    if (st) { STG_A(db, 0, 0, k2); STG_A(db, 1, 0, k2); STG_B(db, 0, 0, k2); }
    __builtin_amdgcn_s_setprio(1);
#pragma unroll
    for (int mf = 0; mf < 4; ++mf)
#pragma unroll
      for (int nf = 2; nf < 4; ++nf)
#pragma unroll
        for (int ks = 0; ks < 2; ++ks)
          acc[mf][nf] = __builtin_amdgcn_mfma_f32_16x16x32_bf16(a0[mf][ks], bq[nf][ks], acc[mf][nf], 0, 0, 0);
    __builtin_amdgcn_s_setprio(0);
    __builtin_amdgcn_sched_barrier(0);
    __builtin_amdgcn_s_barrier();
    asm volatile("" ::: "memory");

    // ============ P3: stage A01,A11,B01; M3 reg-only ============
    if (st) { STG_A(db, 0, 1, k2); STG_A(db, 1, 1, k2); STG_B(db, 0, 1, k2); }
    __builtin_amdgcn_s_setprio(1);
#pragma unroll
    for (int mf = 0; mf < 4; ++mf)
#pragma unroll
      for (int nf = 0; nf < 2; ++nf)
#pragma unroll
        for (int ks = 0; ks < 2; ++ks)
          acc[mf + 4][nf] = __builtin_amdgcn_mfma_f32_16x16x32_bf16(a1[mf][ks], bq[nf][ks], acc[mf + 4][nf], 0, 0, 0);
    __builtin_amdgcn_s_setprio(0);
    __builtin_amdgcn_sched_barrier(0);
    __builtin_amdgcn_s_barrier();
    asm volatile("" ::: "memory");

    // ============ P4: stage B10,B11; M4 reg-only; boundary vmcnt ============
    if (st) { STG_B(db, 1, 0, k2); STG_B(db, 1, 1, k2); }
    __builtin_amdgcn_s_setprio(1);
#pragma unroll
    for (int mf = 0; mf < 4; ++mf)
#pragma unroll
      for (int nf = 2; nf < 4; ++nf)
#pragma unroll
        for (int ks = 0; ks < 2; ++ks)
          acc[mf + 4][nf] = __builtin_amdgcn_mfma_f32_16x16x32_bf16(a1[mf][ks], bq[nf][ks], acc[mf + 4][nf], 0, 0, 0);
    __builtin_amdgcn_s_setprio(0);
    __builtin_amdgcn_sched_barrier(0);
    if (k < nKT - 2) {
      asm volatile("s_waitcnt vmcnt(8)" ::: "memory");  // tile k+1 landed, k+2 in flight
      __builtin_amdgcn_s_barrier();
      asm volatile("" ::: "memory");
    } else if (k == nKT - 2) {
      asm volatile("s_waitcnt vmcnt(0)" ::: "memory");  // last tile landed
      __builtin_amdgcn_s_barrier();
      asm volatile("" ::: "memory");
    }
  }
#undef STG_A
#undef STG_B

  if constexpr (EPI == 0) {
    const int which = n0 >> 10;  // 0=q 1=k 2=v (uniform: 1024 % 256 == 0)
    unsigned short* qk = (which == 0) ? qout : kout;
#pragma unroll
    for (int nf = 0; nf < 4; ++nf) {
      const int o = n0 + wn * 64 + nf * 16 + c;
      const int h = (o >> 6) & 15;
      const int d = o & 63;
      if (which < 2) {
        const float sgn = (d & 1) ? 1.0f : -1.0f;
        const float qscale = (which == 0) ? 0.125f : 1.0f;  // fold D^-0.5 into q
#pragma unroll
        for (int mf = 0; mf < 8; ++mf) {
          const int m = m0 + wm * 128 + mf * 16 + g * 4;
          const int bb = m >> 8;
          const int nb = m & 255;
          f32x4 v = acc[mf][nf];
          f32x4 p;
          p[0] = __shfl_xor(v[0], 1);
          p[1] = __shfl_xor(v[1], 1);
          p[2] = __shfl_xor(v[2], 1);
          p[3] = __shfl_xor(v[3], 1);
          size_t base = ((size_t)(bb * 16 + h) * 256 + nb) * 64 + d;
#pragma unroll
          for (int jj = 0; jj < 4; ++jj) {
            const int n = nb + jj;
            const float cv = cosT[n * 64 + d];
            const float sv = sinT[n * 64 + d];
            float ov = (v[jj] * cv + sgn * p[jj] * sv) * qscale;
            qk[base + (size_t)jj * 64] = f2bf(ov);
          }
        }
      } else {
#pragma unroll
        for (int mf = 0; mf < 8; ++mf) {
          const int m = m0 + wm * 128 + mf * 16 + g * 4;
          const int bb = m >> 8;
          const int nb = m & 255;
          f32x4 v = acc[mf][nf];
          u16x4 pk;
          pk[0] = f2bf(v[0]); pk[1] = f2bf(v[1]); pk[2] = f2bf(v[2]); pk[3] = f2bf(v[3]);
          size_t idx = ((size_t)(bb * 16 + h) * 64 + d) * 256 + nb;  // vT[b,h,d,n]
          *reinterpret_cast<u16x4*>(vTout + idx) = pk;
        }
      }
    }
  } else {
#pragma unroll
    for (int nf = 0; nf < 4; ++nf) {
      const int o = n0 + wn * 64 + nf * 16 + c;
      const float bv = bias[o];
#pragma unroll
      for (int mf = 0; mf < 8; ++mf) {
        const int m = m0 + wm * 128 + mf * 16 + g * 4;
        f32x4 v = acc[mf][nf];
#pragma unroll
        for (int jj = 0; jj < 4; ++jj) fout[(size_t)(m + jj) * N + o] = v[jj] + bv;
      }
    }
  }
}

// ---------------- flash attention, swapped operands (unchanged) ----------------
__global__ __launch_bounds__(256) void k_attn(const unsigned short* __restrict__ Q,
                                              const unsigned short* __restrict__ Kb,
                                              const unsigned short* __restrict__ VT,
                                              unsigned short* __restrict__ Out) {
  constexpr int LDK = 80, LDP = 80;
  __shared__ unsigned short klds[64 * LDK];
  __shared__ unsigned short plds[4][64 * LDP];
  const int bh = blockIdx.x;
  const int bb = bh >> 4, h = bh & 15;
  const int t = threadIdx.x, w = t >> 6, l = t & 63, c = l & 15, g = l >> 4;
  const unsigned short* qh = Q + (size_t)bh * 256 * 64;
  const unsigned short* kh = Kb + (size_t)bh * 256 * 64;
  const unsigned short* vh = VT + (size_t)bh * 64 * 256;
  const int q0 = w * 64;

  bf16x8 qf[4][2];
#pragma unroll
  for (int nf = 0; nf < 4; ++nf)
#pragma unroll
    for (int ks = 0; ks < 2; ++ks)
      qf[nf][ks] = *reinterpret_cast<const bf16x8*>(qh + (q0 + nf * 16 + c) * 64 + ks * 32 + g * 8);

  f32x4 oacc[4][4];
#pragma unroll
  for (int i = 0; i < 4; ++i)
#pragma unroll
    for (int jj = 0; jj < 4; ++jj) oacc[i][jj] = 0.0f;
  float mr[4] = {-1e30f, -1e30f, -1e30f, -1e30f};
  float lr[4] = {0.f, 0.f, 0.f, 0.f};

  for (int ch = 0; ch < 4; ++ch) {
    __syncthreads();
    {
      int row = t >> 3, col = (t & 7) * 8;
#pragma unroll
      for (int rep = 0; rep < 2; ++rep) {
        int r = rep * 32 + row;
        bf16x8 kv = *reinterpret_cast<const bf16x8*>(kh + (ch * 64 + r) * 64 + col);
        *reinterpret_cast<bf16x8*>(&klds[r * LDK + col]) = kv;
      }
    }
    __syncthreads();

    f32x4 s[4][4];
#pragma unroll
    for (int i = 0; i < 4; ++i)
#pragma unroll
      for (int jj = 0; jj < 4; ++jj) s[i][jj] = 0.0f;
#pragma unroll
    for (int ks = 0; ks < 2; ++ks) {
      bf16x8 kf[4];
#pragma unroll
      for (int mf = 0; mf < 4; ++mf)
        kf[mf] = *reinterpret_cast<const bf16x8*>(&klds[(mf * 16 + c) * LDK + ks * 32 + g * 8]);
#pragma unroll
      for (int mf = 0; mf < 4; ++mf)
#pragma unroll
        for (int nf = 0; nf < 4; ++nf)
          s[mf][nf] = __builtin_amdgcn_mfma_f32_16x16x32_bf16(kf[mf], qf[nf][ks], s[mf][nf], 0, 0, 0);
    }

#pragma unroll
    for (int nf = 0; nf < 4; ++nf) {
      float mx = -1e30f;
#pragma unroll
      for (int mf = 0; mf < 4; ++mf)
#pragma unroll
        for (int jj = 0; jj < 4; ++jj) mx = fmaxf(mx, s[mf][nf][jj]);
      mx = fmaxf(mx, __shfl_xor(mx, 16));
      mx = fmaxf(mx, __shfl_xor(mx, 32));
      float mnew = fmaxf(mr[nf], mx);
      float rsc = __expf(mr[nf] - mnew);
      mr[nf] = mnew;
      float sum = 0.f;
#pragma unroll
      for (int mf = 0; mf < 4; ++mf)
#pragma unroll
        for (int jj = 0; jj < 4; ++jj) {
          float p = __expf(s[mf][nf][jj] - mnew);
          s[mf][nf][jj] = p;
          sum += p;
        }
      sum += __shfl_xor(sum, 16);
      sum += __shfl_xor(sum, 32);
      lr[nf] = lr[nf] * rsc + sum;
#pragma unroll
      for (int mf = 0; mf < 4; ++mf) oacc[mf][nf] *= rsc;
    }

#pragma unroll
    for (int mf = 0; mf < 4; ++mf)
#pragma unroll
      for (int nf = 0; nf < 4; ++nf) {
        bf16x4 pk;
        pk[0] = (short)f2bf(s[mf][nf][0]);
        pk[1] = (short)f2bf(s[mf][nf][1]);
        pk[2] = (short)f2bf(s[mf][nf][2]);
        pk[3] = (short)f2bf(s[mf][nf][3]);
        *reinterpret_cast<bf16x4*>(&plds[w][(nf * 16 + c) * LDP + mf * 16 + g * 4]) = pk;
      }

#pragma unroll
    for (int ks = 0; ks < 2; ++ks) {
      bf16x8 vf[4], pf[4];
#pragma unroll
      for (int mf = 0; mf < 4; ++mf)
        vf[mf] = *reinterpret_cast<const bf16x8*>(vh + (mf * 16 + c) * 256 + ch * 64 + ks * 32 + g * 8);
#pragma unroll
      for (int nf = 0; nf < 4; ++nf) {
        bf16x4 p0 = *reinterpret_cast<const bf16x4*>(&plds[w][(nf * 16 + c) * LDP + ks * 32 + g * 8]);
        bf16x4 p1 = *reinterpret_cast<const bf16x4*>(&plds[w][(nf * 16 + c) * LDP + ks * 32 + g * 8 + 4]);
        pf[nf] = __builtin_shufflevector(p0, p1, 0, 1, 2, 3, 4, 5, 6, 7);
      }
#pragma unroll
      for (int mf = 0; mf < 4; ++mf)
#pragma unroll
        for (int nf = 0; nf < 4; ++nf)
          oacc[mf][nf] = __builtin_amdgcn_mfma_f32_16x16x32_bf16(vf[mf], pf[nf], oacc[mf][nf], 0, 0, 0);
    }
  }

  float linv[4];
#pragma unroll
  for (int nf = 0; nf < 4; ++nf) linv[nf] = 1.0f / lr[nf];
#pragma unroll
  for (int mf = 0; mf < 4; ++mf)
#pragma unroll
    for (int nf = 0; nf < 4; ++nf) {
      f32x4 v = oacc[mf][nf];
      u16x4 pk;
      pk[0] = f2bf(v[0] * linv[nf]);
      pk[1] = f2bf(v[1] * linv[nf]);
      pk[2] = f2bf(v[2] * linv[nf]);
      pk[3] = f2bf(v[3] * linv[nf]);
      size_t row = (size_t)bb * 256 + q0 + nf * 16 + c;
      size_t idx = row * 1024 + (size_t)h * 64 + mf * 16 + g * 4;  // out[b,n, h*64+d]
      *reinterpret_cast<u16x4*>(Out + idx) = pk;
    }
}

extern "C" void kernel_launch(void* const* d_in, const int* in_sizes, int n_in,
                              void* d_out, int out_size, void* d_ws, size_t ws_size,
                              hipStream_t stream) {
  const float* x = (const float*)d_in[0];
  const float* wqkv = (const float*)d_in[1];
  const float* wproj = (const float*)d_in[2];
  const float* bproj = (const float*)d_in[3];

  char* ws = (char*)d_ws;
  unsigned short* xb = (unsigned short*)(ws);                 // 33,554,432 B (reused as attn_out)
  unsigned short* wqkvb = (unsigned short*)(ws + 33554432);   //  6,291,456 B
  unsigned short* wprojb = (unsigned short*)(ws + 39845888);  //  2,097,152 B
  float* cosT = (float*)(ws + 41943040);                      //     65,536 B
  float* sinT = (float*)(ws + 42008576);                      //     65,536 B
  unsigned short* qb = (unsigned short*)(ws + 42074112);      // 33,554,432 B
  unsigned short* kb = (unsigned short*)(ws + 75628544);      // 33,554,432 B
  unsigned short* vtb = (unsigned short*)(ws + 109182976);    // 33,554,432 B -> total 142,737,408 B
  unsigned short* attn_out = xb;

  k_cvt<<<16384, 256, 0, stream>>>(x, xb, 4194304);
  k_cvt<<<3072, 256, 0, stream>>>(wqkv, wqkvb, 786432);
  k_cvt<<<1024, 256, 0, stream>>>(wproj, wprojb, 262144);
  k_tables<<<1, 256, 0, stream>>>(cosT, sinT);

  // QKV: M=16384 (64 tiles), N=3072 (12 tiles), K=1024; RoPE epilogue. grid=768 (%8==0)
  k_gemm<0><<<64 * 12, 512, 0, stream>>>(xb, wqkvb, 16384, 3072, 1024, 64,
                                         cosT, sinT, qb, kb, vtb, nullptr, nullptr);
  // attention: one block per (b,h)
  k_attn<<<1024, 256, 0, stream>>>(qb, kb, vtb, attn_out);
  // proj: M=16384 (64 tiles), N=1024 (4 tiles), K=1024, +bias, fp32 out. grid=256 (%8==0)
  k_gemm<1><<<64 * 4, 512, 0, stream>>>(attn_out, wprojb, 16384, 1024, 1024, 64,
                                        nullptr, nullptr, nullptr, nullptr, nullptr,
                                        bproj, (float*)d_out);
}

// Round 6
// 285.972 us; speedup vs baseline: 1.2635x; 1.0456x over previous
//
#include <hip/hip_runtime.h>
#include <stdint.h>

typedef __attribute__((ext_vector_type(8))) short bf16x8;
typedef __attribute__((ext_vector_type(4))) short bf16x4;
typedef __attribute__((ext_vector_type(4))) float f32x4;
typedef __attribute__((ext_vector_type(4))) unsigned short u16x4;

typedef __attribute__((address_space(3))) unsigned short lds_u16;
typedef const __attribute__((address_space(1))) unsigned short glb_u16;

__device__ __forceinline__ unsigned short f2bf(float f) {
  union { float f; unsigned u; } x; x.f = f;
  unsigned r = x.u + 0x7FFFu + ((x.u >> 16) & 1u);
  return (unsigned short)(r >> 16);
}

// ---------------- fp32 -> bf16 convert (x4 vectorized) ----------------
__global__ __launch_bounds__(256) void k_cvt(const float* __restrict__ in,
                                             unsigned short* __restrict__ out, int n4) {
  int i = blockIdx.x * 256 + threadIdx.x;
  if (i >= n4) return;
  f32x4 v = reinterpret_cast<const f32x4*>(in)[i];
  u16x4 o;
  o[0] = f2bf(v[0]); o[1] = f2bf(v[1]); o[2] = f2bf(v[2]); o[3] = f2bf(v[3]);
  reinterpret_cast<u16x4*>(out)[i] = o;
}

// ---------------- RoPE cos/sin tables: (256, 64) ----------------
__global__ void k_tables(float* __restrict__ cosT, float* __restrict__ sinT) {
  int n = threadIdx.x;
  int r = n >> 4, cc = n & 15;
  for (int d = 0; d < 64; ++d) {
    int tpos = (d < 32) ? r : cc;
    int j = (d & 31) >> 1;
    float ang = (float)tpos * powf(10000.0f, -(float)j * (1.0f / 16.0f));
    cosT[n * 64 + d] = cosf(ang);
    sinT[n * 64 + d] = sinf(ang);
  }
}

// ============ 256x256xBK64, 8-wave (2x4), pipelined-read phase GEMM ============
// Reads issued one phase ahead of use (R1=a0+b_lo in prev P4 post-boundary; R2=b_hi in
// P1; R3=a1 in P2); counted lgkm waits; stages placed one phase after the lgkm-wait
// that covered the region's reads (A*0->P2, B->P3, A*1->P4); boundary vmcnt(8)+barrier
// mid-P4 before R1-next issue. LDS issue spread 4/8/0/12 per phase.
template <int EPI>
__global__ __launch_bounds__(512, 2) void k_gemm(
    const unsigned short* __restrict__ A,  // M x K bf16
    const unsigned short* __restrict__ B,  // N x K bf16 (B^T layout)
    int M, int N, int K, int nTM,
    const float* __restrict__ cosT, const float* __restrict__ sinT,
    unsigned short* __restrict__ qout, unsigned short* __restrict__ kout,
    unsigned short* __restrict__ vTout,
    const float* __restrict__ bias, float* __restrict__ fout) {
  __shared__ unsigned short smem_u16[65536];  // 128 KiB

  const int t = threadIdx.x, w = t >> 6, l = t & 63, c = l & 15, g = l >> 4;
  const int wm = w >> 2, wn = w & 3;

  // L2-locality mapping: each XCD owns an A-band of nTM/8 row-tiles, tn fastest.
  const int nwg = gridDim.x;
  const int bid = (int)blockIdx.x;
  const int nTN = nwg / nTM;
  const int xcd = bid & 7;
  const int j = bid >> 3;
  const int tn = j % nTN;
  const int tm = xcd * (nTM >> 3) + j / nTN;
  const int m0 = tm * 256, n0 = tn * 256;

  // ---- stage source (pre-swizzled): thread t covers one 16B chunk of an 8192B issue
  const int rS = t >> 3;                                   // row 0..63 within chunk
  const int colS = ((t & 7) * 8) ^ (((t >> 5) & 1) << 4);  // element col, swizzled
  const unsigned short* Asrc = A + (size_t)(m0 + rS) * K + colS;
  const unsigned short* Bsrc = B + (size_t)(n0 + rS) * K + colS;
  const size_t hK = (size_t)128 * K;  // half-tile row skip
  const size_t iK = (size_t)64 * K;   // chunk row skip

#define STG_A(db, half, i, kt)                                                              \
  __builtin_amdgcn_global_load_lds((glb_u16*)(Asrc + (half) * hK + (i) * iK + (kt) * 64),   \
      (lds_u16*)&smem_u16[((db) * 32768 + (half) * 16384 + (i) * 8192 + w * 1024) >> 1],    \
      16, 0, 0)
#define STG_B(db, half, i, kt)                                                                      \
  __builtin_amdgcn_global_load_lds((glb_u16*)(Bsrc + (half) * hK + (i) * iK + (kt) * 64),           \
      (lds_u16*)&smem_u16[(65536 + (db) * 32768 + (half) * 16384 + (i) * 8192 + w * 1024) >> 1],    \
      16, 0, 0)

  // prologue: stage K-tiles 0 (buf0) and 1 (buf1) = 16 loads/wave
#pragma unroll
  for (int kk = 0; kk < 2; ++kk) {
    STG_A(kk, 0, 0, kk); STG_A(kk, 0, 1, kk); STG_A(kk, 1, 0, kk); STG_A(kk, 1, 1, kk);
    STG_B(kk, 0, 0, kk); STG_B(kk, 0, 1, kk); STG_B(kk, 1, 0, kk); STG_B(kk, 1, 1, kk);
  }

  f32x4 acc[8][4];
#pragma unroll
  for (int i = 0; i < 8; ++i)
#pragma unroll
    for (int jj = 0; jj < 4; ++jj) acc[i][jj] = 0.0f;

  // ---- fragment read addressing (swizzled): flip bit5 of k-offset when (row>>2)&1
  const int xm = ((c >> 2) & 1) << 5;
  const int ko0 = (g * 16) ^ xm;  // ks=0 byte offset within 128B row
  const int ko1 = ko0 + 64;       // ks=1 (bit6 unaffected by xm)
  const int rAb = (wm * 128 + c) * 128;  // byte row base (+ mf*2048)
  const int rBb = (wn * 64 + c) * 128;   // byte row base (+ nf*2048)

  bf16x8 a0[4][2], a1[4][2], bq[4][2];

#define RD_A0(Abo)                                                                       \
  _Pragma("unroll") for (int mf = 0; mf < 4; ++mf) {                                     \
    a0[mf][0] = *(const bf16x8*)&smem_u16[((Abo) + rAb + mf * 2048 + ko0) >> 1];         \
    a0[mf][1] = *(const bf16x8*)&smem_u16[((Abo) + rAb + mf * 2048 + ko1) >> 1];         \
  }
#define RD_A1(Abo)                                                                       \
  _Pragma("unroll") for (int mf = 0; mf < 4; ++mf) {                                     \
    a1[mf][0] = *(const bf16x8*)&smem_u16[((Abo) + rAb + (mf + 4) * 2048 + ko0) >> 1];   \
    a1[mf][1] = *(const bf16x8*)&smem_u16[((Abo) + rAb + (mf + 4) * 2048 + ko1) >> 1];   \
  }
#define RD_BLO(Bbo)                                                                      \
  _Pragma("unroll") for (int nf = 0; nf < 2; ++nf) {                                     \
    bq[nf][0] = *(const bf16x8*)&smem_u16[((Bbo) + rBb + nf * 2048 + ko0) >> 1];         \
    bq[nf][1] = *(const bf16x8*)&smem_u16[((Bbo) + rBb + nf * 2048 + ko1) >> 1];         \
  }
#define RD_BHI(Bbo)                                                                      \
  _Pragma("unroll") for (int nf = 2; nf < 4; ++nf) {                                     \
    bq[nf][0] = *(const bf16x8*)&smem_u16[((Bbo) + rBb + nf * 2048 + ko0) >> 1];         \
    bq[nf][1] = *(const bf16x8*)&smem_u16[((Bbo) + rBb + nf * 2048 + ko1) >> 1];         \
  }
#define MFMA_Q(am, bl, bh, mo)                                                           \
  __builtin_amdgcn_s_setprio(1);                                                         \
  _Pragma("unroll") for (int mf = 0; mf < 4; ++mf)                                       \
  _Pragma("unroll") for (int nf = (bl); nf < (bh); ++nf)                                 \
  _Pragma("unroll") for (int ks = 0; ks < 2; ++ks)                                       \
      acc[mf + (mo)][nf] =                                                               \
          __builtin_amdgcn_mfma_f32_16x16x32_bf16(am[mf][ks], bq[nf][ks], acc[mf + (mo)][nf], 0, 0, 0); \
  __builtin_amdgcn_s_setprio(0);                                                         \
  __builtin_amdgcn_sched_barrier(0)

  asm volatile("s_waitcnt vmcnt(8)" ::: "memory");  // tile 0 landed; tile 1 in flight
  __builtin_amdgcn_s_barrier();
  asm volatile("" ::: "memory");
  RD_A0(0);        // R1 for k=0 (buf0)
  RD_BLO(65536);

  const int nKT = K >> 6;
  for (int k = 0; k < nKT; ++k) {
    const int db = k & 1;
    const int Abo = db * 32768;
    const int Bbo = 65536 + db * 32768;
    const int nAbo = (db ^ 1) * 32768;
    const int nBbo = 65536 + (db ^ 1) * 32768;
    const int k2 = k + 2;
    const bool st = (k2 < nKT);

    // ---- P1: lgkm(0) [R1 done]; issue R2=b_hi; MFMA Q11
    asm volatile("s_waitcnt lgkmcnt(0)" ::: "memory");
    RD_BHI(Bbo);
    MFMA_Q(a0, 0, 2, 0);
    __builtin_amdgcn_s_barrier();
    asm volatile("" ::: "memory");

    // ---- P2: issue R3=a1; lgkm(8) [R2 done, R3 in flight]; stage A*0; MFMA Q12
    RD_A1(Abo);
    asm volatile("s_waitcnt lgkmcnt(8)" ::: "memory");
    if (st) { STG_A(db, 0, 0, k2); STG_A(db, 1, 0, k2); }
    MFMA_Q(a0, 2, 4, 0);
    __builtin_amdgcn_s_barrier();
    asm volatile("" ::: "memory");

    // ---- P3: lgkm(0) [R3 done]; stage B (all); MFMA Q21
    asm volatile("s_waitcnt lgkmcnt(0)" ::: "memory");
    if (st) { STG_B(db, 0, 0, k2); STG_B(db, 0, 1, k2); STG_B(db, 1, 0, k2); STG_B(db, 1, 1, k2); }
    MFMA_Q(a1, 0, 2, 4);
    __builtin_amdgcn_s_barrier();
    asm volatile("" ::: "memory");

    // ---- P4: stage A*1; boundary vmcnt+barrier; issue R1-next; MFMA Q22
    if (st) { STG_A(db, 0, 1, k2); STG_A(db, 1, 1, k2); }
    if (k < nKT - 2) {
      asm volatile("s_waitcnt vmcnt(8)" ::: "memory");  // tile k+1 landed, k+2 in flight
    } else if (k == nKT - 2) {
      asm volatile("s_waitcnt vmcnt(0)" ::: "memory");  // last tile landed
    }
    __builtin_amdgcn_s_barrier();
    asm volatile("" ::: "memory");
    if (k + 1 < nKT) { RD_A0(nAbo); RD_BLO(nBbo); }  // R1 for k+1 (safe: tile landed)
    MFMA_Q(a1, 2, 4, 4);
    __builtin_amdgcn_s_barrier();
    asm volatile("" ::: "memory");
  }
#undef STG_A
#undef STG_B
#undef RD_A0
#undef RD_A1
#undef RD_BLO
#undef RD_BHI
#undef MFMA_Q

  if constexpr (EPI == 0) {
    const int which = n0 >> 10;  // 0=q 1=k 2=v (uniform: 1024 % 256 == 0)
    unsigned short* qk = (which == 0) ? qout : kout;
#pragma unroll
    for (int nf = 0; nf < 4; ++nf) {
      const int o = n0 + wn * 64 + nf * 16 + c;
      const int h = (o >> 6) & 15;
      const int d = o & 63;
      if (which < 2) {
        const float sgn = (d & 1) ? 1.0f : -1.0f;
        const float qscale = (which == 0) ? 0.125f : 1.0f;  // fold D^-0.5 into q
#pragma unroll
        for (int mf = 0; mf < 8; ++mf) {
          const int m = m0 + wm * 128 + mf * 16 + g * 4;
          const int bb = m >> 8;
          const int nb = m & 255;
          f32x4 v = acc[mf][nf];
          f32x4 p;
          p[0] = __shfl_xor(v[0], 1);
          p[1] = __shfl_xor(v[1], 1);
          p[2] = __shfl_xor(v[2], 1);
          p[3] = __shfl_xor(v[3], 1);
          size_t base = ((size_t)(bb * 16 + h) * 256 + nb) * 64 + d;
#pragma unroll
          for (int jj = 0; jj < 4; ++jj) {
            const int n = nb + jj;
            const float cv = cosT[n * 64 + d];
            const float sv = sinT[n * 64 + d];
            float ov = (v[jj] * cv + sgn * p[jj] * sv) * qscale;
            qk[base + (size_t)jj * 64] = f2bf(ov);
          }
        }
      } else {
#pragma unroll
        for (int mf = 0; mf < 8; ++mf) {
          const int m = m0 + wm * 128 + mf * 16 + g * 4;
          const int bb = m >> 8;
          const int nb = m & 255;
          f32x4 v = acc[mf][nf];
          u16x4 pk;
          pk[0] = f2bf(v[0]); pk[1] = f2bf(v[1]); pk[2] = f2bf(v[2]); pk[3] = f2bf(v[3]);
          size_t idx = ((size_t)(bb * 16 + h) * 64 + d) * 256 + nb;  // vT[b,h,d,n]
          *reinterpret_cast<u16x4*>(vTout + idx) = pk;
        }
      }
    }
  } else {
#pragma unroll
    for (int nf = 0; nf < 4; ++nf) {
      const int o = n0 + wn * 64 + nf * 16 + c;
      const float bv = bias[o];
#pragma unroll
      for (int mf = 0; mf < 8; ++mf) {
        const int m = m0 + wm * 128 + mf * 16 + g * 4;
        f32x4 v = acc[mf][nf];
#pragma unroll
        for (int jj = 0; jj < 4; ++jj) fout[(size_t)(m + jj) * N + o] = v[jj] + bv;
      }
    }
  }
}

// ---------------- flash attention, swapped operands (unchanged) ----------------
__global__ __launch_bounds__(256) void k_attn(const unsigned short* __restrict__ Q,
                                              const unsigned short* __restrict__ Kb,
                                              const unsigned short* __restrict__ VT,
                                              unsigned short* __restrict__ Out) {
  constexpr int LDK = 80, LDP = 80;
  __shared__ unsigned short klds[64 * LDK];
  __shared__ unsigned short plds[4][64 * LDP];
  const int bh = blockIdx.x;
  const int bb = bh >> 4, h = bh & 15;
  const int t = threadIdx.x, w = t >> 6, l = t & 63, c = l & 15, g = l >> 4;
  const unsigned short* qh = Q + (size_t)bh * 256 * 64;
  const unsigned short* kh = Kb + (size_t)bh * 256 * 64;
  const unsigned short* vh = VT + (size_t)bh * 64 * 256;
  const int q0 = w * 64;

  bf16x8 qf[4][2];
#pragma unroll
  for (int nf = 0; nf < 4; ++nf)
#pragma unroll
    for (int ks = 0; ks < 2; ++ks)
      qf[nf][ks] = *reinterpret_cast<const bf16x8*>(qh + (q0 + nf * 16 + c) * 64 + ks * 32 + g * 8);

  f32x4 oacc[4][4];
#pragma unroll
  for (int i = 0; i < 4; ++i)
#pragma unroll
    for (int jj = 0; jj < 4; ++jj) oacc[i][jj] = 0.0f;
  float mr[4] = {-1e30f, -1e30f, -1e30f, -1e30f};
  float lr[4] = {0.f, 0.f, 0.f, 0.f};

  for (int ch = 0; ch < 4; ++ch) {
    __syncthreads();
    {
      int row = t >> 3, col = (t & 7) * 8;
#pragma unroll
      for (int rep = 0; rep < 2; ++rep) {
        int r = rep * 32 + row;
        bf16x8 kv = *reinterpret_cast<const bf16x8*>(kh + (ch * 64 + r) * 64 + col);
        *reinterpret_cast<bf16x8*>(&klds[r * LDK + col]) = kv;
      }
    }
    __syncthreads();

    f32x4 s[4][4];
#pragma unroll
    for (int i = 0; i < 4; ++i)
#pragma unroll
      for (int jj = 0; jj < 4; ++jj) s[i][jj] = 0.0f;
#pragma unroll
    for (int ks = 0; ks < 2; ++ks) {
      bf16x8 kf[4];
#pragma unroll
      for (int mf = 0; mf < 4; ++mf)
        kf[mf] = *reinterpret_cast<const bf16x8*>(&klds[(mf * 16 + c) * LDK + ks * 32 + g * 8]);
#pragma unroll
      for (int mf = 0; mf < 4; ++mf)
#pragma unroll
        for (int nf = 0; nf < 4; ++nf)
          s[mf][nf] = __builtin_amdgcn_mfma_f32_16x16x32_bf16(kf[mf], qf[nf][ks], s[mf][nf], 0, 0, 0);
    }

#pragma unroll
    for (int nf = 0; nf < 4; ++nf) {
      float mx = -1e30f;
#pragma unroll
      for (int mf = 0; mf < 4; ++mf)
#pragma unroll
        for (int jj = 0; jj < 4; ++jj) mx = fmaxf(mx, s[mf][nf][jj]);
      mx = fmaxf(mx, __shfl_xor(mx, 16));
      mx = fmaxf(mx, __shfl_xor(mx, 32));
      float mnew = fmaxf(mr[nf], mx);
      float rsc = __expf(mr[nf] - mnew);
      mr[nf] = mnew;
      float sum = 0.f;
#pragma unroll
      for (int mf = 0; mf < 4; ++mf)
#pragma unroll
        for (int jj = 0; jj < 4; ++jj) {
          float p = __expf(s[mf][nf][jj] - mnew);
          s[mf][nf][jj] = p;
          sum += p;
        }
      sum += __shfl_xor(sum, 16);
      sum += __shfl_xor(sum, 32);
      lr[nf] = lr[nf] * rsc + sum;
#pragma unroll
      for (int mf = 0; mf < 4; ++mf) oacc[mf][nf] *= rsc;
    }

#pragma unroll
    for (int mf = 0; mf < 4; ++mf)
#pragma unroll
      for (int nf = 0; nf < 4; ++nf) {
        bf16x4 pk;
        pk[0] = (short)f2bf(s[mf][nf][0]);
        pk[1] = (short)f2bf(s[mf][nf][1]);
        pk[2] = (short)f2bf(s[mf][nf][2]);
        pk[3] = (short)f2bf(s[mf][nf][3]);
        *reinterpret_cast<bf16x4*>(&plds[w][(nf * 16 + c) * LDP + mf * 16 + g * 4]) = pk;
      }

#pragma unroll
    for (int ks = 0; ks < 2; ++ks) {
      bf16x8 vf[4], pf[4];
#pragma unroll
      for (int mf = 0; mf < 4; ++mf)
        vf[mf] = *reinterpret_cast<const bf16x8*>(vh + (mf * 16 + c) * 256 + ch * 64 + ks * 32 + g * 8);
#pragma unroll
      for (int nf = 0; nf < 4; ++nf) {
        bf16x4 p0 = *reinterpret_cast<const bf16x4*>(&plds[w][(nf * 16 + c) * LDP + ks * 32 + g * 8]);
        bf16x4 p1 = *reinterpret_cast<const bf16x4*>(&plds[w][(nf * 16 + c) * LDP + ks * 32 + g * 8 + 4]);
        pf[nf] = __builtin_shufflevector(p0, p1, 0, 1, 2, 3, 4, 5, 6, 7);
      }
#pragma unroll
      for (int mf = 0; mf < 4; ++mf)
#pragma unroll
        for (int nf = 0; nf < 4; ++nf)
          oacc[mf][nf] = __builtin_amdgcn_mfma_f32_16x16x32_bf16(vf[mf], pf[nf], oacc[mf][nf], 0, 0, 0);
    }
  }

  float linv[4];
#pragma unroll
  for (int nf = 0; nf < 4; ++nf) linv[nf] = 1.0f / lr[nf];
#pragma unroll
  for (int mf = 0; mf < 4; ++mf)
#pragma unroll
    for (int nf = 0; nf < 4; ++nf) {
      f32x4 v = oacc[mf][nf];
      u16x4 pk;
      pk[0] = f2bf(v[0] * linv[nf]);
      pk[1] = f2bf(v[1] * linv[nf]);
      pk[2] = f2bf(v[2] * linv[nf]);
      pk[3] = f2bf(v[3] * linv[nf]);
      size_t row = (size_t)bb * 256 + q0 + nf * 16 + c;
      size_t idx = row * 1024 + (size_t)h * 64 + mf * 16 + g * 4;  // out[b,n, h*64+d]
      *reinterpret_cast<u16x4*>(Out + idx) = pk;
    }
}

extern "C" void kernel_launch(void* const* d_in, const int* in_sizes, int n_in,
                              void* d_out, int out_size, void* d_ws, size_t ws_size,
                              hipStream_t stream) {
  const float* x = (const float*)d_in[0];
  const float* wqkv = (const float*)d_in[1];
  const float* wproj = (const float*)d_in[2];
  const float* bproj = (const float*)d_in[3];

  char* ws = (char*)d_ws;
  unsigned short* xb = (unsigned short*)(ws);                 // 33,554,432 B (reused as attn_out)
  unsigned short* wqkvb = (unsigned short*)(ws + 33554432);   //  6,291,456 B
  unsigned short* wprojb = (unsigned short*)(ws + 39845888);  //  2,097,152 B
  float* cosT = (float*)(ws + 41943040);                      //     65,536 B
  float* sinT = (float*)(ws + 42008576);                      //     65,536 B
  unsigned short* qb = (unsigned short*)(ws + 42074112);      // 33,554,432 B
  unsigned short* kb = (unsigned short*)(ws + 75628544);      // 33,554,432 B
  unsigned short* vtb = (unsigned short*)(ws + 109182976);    // 33,554,432 B -> total 142,737,408 B
  unsigned short* attn_out = xb;

  k_cvt<<<16384, 256, 0, stream>>>(x, xb, 4194304);
  k_cvt<<<3072, 256, 0, stream>>>(wqkv, wqkvb, 786432);
  k_cvt<<<1024, 256, 0, stream>>>(wproj, wprojb, 262144);
  k_tables<<<1, 256, 0, stream>>>(cosT, sinT);

  // QKV: M=16384 (64 tiles), N=3072 (12 tiles), K=1024; RoPE epilogue. grid=768 (%8==0)
  k_gemm<0><<<64 * 12, 512, 0, stream>>>(xb, wqkvb, 16384, 3072, 1024, 64,
                                         cosT, sinT, qb, kb, vtb, nullptr, nullptr);
  // attention: one block per (b,h)
  k_attn<<<1024, 256, 0, stream>>>(qb, kb, vtb, attn_out);
  // proj: M=16384 (64 tiles), N=1024 (4 tiles), K=1024, +bias, fp32 out. grid=256 (%8==0)
  k_gemm<1><<<64 * 4, 512, 0, stream>>>(attn_out, wprojb, 16384, 1024, 1024, 64,
                                        nullptr, nullptr, nullptr, nullptr, nullptr,
                                        bproj, (float*)d_out);
}

// Round 7
// 282.384 us; speedup vs baseline: 1.2796x; 1.0127x over previous
//
#include <hip/hip_runtime.h>
#include <stdint.h>

typedef __attribute__((ext_vector_type(8))) short bf16x8;
typedef __attribute__((ext_vector_type(4))) short bf16x4;
typedef __attribute__((ext_vector_type(4))) float f32x4;
typedef __attribute__((ext_vector_type(4))) unsigned short u16x4;

typedef __attribute__((address_space(3))) unsigned short lds_u16;
typedef const __attribute__((address_space(1))) unsigned short glb_u16;

__device__ __forceinline__ unsigned short f2bf(float f) {
  union { float f; unsigned u; } x; x.f = f;
  unsigned r = x.u + 0x7FFFu + ((x.u >> 16) & 1u);
  return (unsigned short)(r >> 16);
}

// ---------------- fp32 -> bf16 convert (x4 vectorized) ----------------
__global__ __launch_bounds__(256) void k_cvt(const float* __restrict__ in,
                                             unsigned short* __restrict__ out, int n4) {
  int i = blockIdx.x * 256 + threadIdx.x;
  if (i >= n4) return;
  f32x4 v = reinterpret_cast<const f32x4*>(in)[i];
  u16x4 o;
  o[0] = f2bf(v[0]); o[1] = f2bf(v[1]); o[2] = f2bf(v[2]); o[3] = f2bf(v[3]);
  reinterpret_cast<u16x4*>(out)[i] = o;
}

// ---------------- RoPE cos/sin tables: (256, 64) ----------------
__global__ void k_tables(float* __restrict__ cosT, float* __restrict__ sinT) {
  int n = threadIdx.x;
  int r = n >> 4, cc = n & 15;
  for (int d = 0; d < 64; ++d) {
    int tpos = (d < 32) ? r : cc;
    int j = (d & 31) >> 1;
    float ang = (float)tpos * powf(10000.0f, -(float)j * (1.0f / 16.0f));
    cosT[n * 64 + d] = cosf(ang);
    sinT[n * 64 + d] = sinf(ang);
  }
}

// ============ 256x256xBK64, 8-wave (2x4), pipelined-read phase GEMM ============
// LDS swizzle: physical 16B-slot = logical_slot ^ (row&7) (full 8-slot spread -> all
// 32 banks active per b128 wavefront read; structural-minimum 8 cyc). Applied as
// pre-swizzled global source (linear gload_lds dest) + XOR on ds_read address.
// Schedule (r6): reads one phase ahead (R1=a0+b_lo prev-P4; R2=b_hi P1; R3=a1 P2);
// counted lgkm; stages one phase after the covering lgkm-wait; boundary vmcnt(8).
template <int EPI>
__global__ __launch_bounds__(512, 2) void k_gemm(
    const unsigned short* __restrict__ A,  // M x K bf16
    const unsigned short* __restrict__ B,  // N x K bf16 (B^T layout)
    int M, int N, int K, int nTM,
    const float* __restrict__ cosT, const float* __restrict__ sinT,
    unsigned short* __restrict__ qout, unsigned short* __restrict__ kout,
    unsigned short* __restrict__ vTout,
    const float* __restrict__ bias, float* __restrict__ fout) {
  __shared__ unsigned short smem_u16[65536];  // 128 KiB

  const int t = threadIdx.x, w = t >> 6, l = t & 63, c = l & 15, g = l >> 4;
  const int wm = w >> 2, wn = w & 3;

  // L2-locality mapping: each XCD owns an A-band of nTM/8 row-tiles, tn fastest.
  const int nwg = gridDim.x;
  const int bid = (int)blockIdx.x;
  const int nTN = nwg / nTM;
  const int xcd = bid & 7;
  const int j = bid >> 3;
  const int tn = j % nTN;
  const int tm = xcd * (nTM >> 3) + j / nTN;
  const int m0 = tm * 256, n0 = tn * 256;

  // ---- stage source (pre-swizzled): thread t covers one 16B chunk of an 8192B issue.
  // physical slot (t&7) of row (t>>3) holds logical slot (t&7)^(row&7).
  const int rS = t >> 3;                                 // row 0..63 within chunk
  const int colS = (((t & 7) ^ ((t >> 3) & 7)) * 8);     // element col (pre-swizzled)
  const unsigned short* Asrc = A + (size_t)(m0 + rS) * K + colS;
  const unsigned short* Bsrc = B + (size_t)(n0 + rS) * K + colS;
  const size_t hK = (size_t)128 * K;  // half-tile row skip
  const size_t iK = (size_t)64 * K;   // chunk row skip

#define STG_A(db, half, i, kt)                                                              \
  __builtin_amdgcn_global_load_lds((glb_u16*)(Asrc + (half) * hK + (i) * iK + (kt) * 64),   \
      (lds_u16*)&smem_u16[((db) * 32768 + (half) * 16384 + (i) * 8192 + w * 1024) >> 1],    \
      16, 0, 0)
#define STG_B(db, half, i, kt)                                                                      \
  __builtin_amdgcn_global_load_lds((glb_u16*)(Bsrc + (half) * hK + (i) * iK + (kt) * 64),           \
      (lds_u16*)&smem_u16[(65536 + (db) * 32768 + (half) * 16384 + (i) * 8192 + w * 1024) >> 1],    \
      16, 0, 0)

  // prologue: stage K-tiles 0 (buf0) and 1 (buf1) = 16 loads/wave
#pragma unroll
  for (int kk = 0; kk < 2; ++kk) {
    STG_A(kk, 0, 0, kk); STG_A(kk, 0, 1, kk); STG_A(kk, 1, 0, kk); STG_A(kk, 1, 1, kk);
    STG_B(kk, 0, 0, kk); STG_B(kk, 0, 1, kk); STG_B(kk, 1, 0, kk); STG_B(kk, 1, 1, kk);
  }

  f32x4 acc[8][4];
#pragma unroll
  for (int i = 0; i < 8; ++i)
#pragma unroll
    for (int jj = 0; jj < 4; ++jj) acc[i][jj] = 0.0f;

  // ---- fragment read addressing: physical byte = logical kbyte ^ ((row&7)<<4);
  // row&7 == c&7 for all fragment rows (all other row terms are multiples of 8/16).
  const int xm7 = (c & 7) << 4;
  const int ko0 = (g * 16) ^ xm7;         // ks=0 byte offset within 128B row
  const int ko1 = (g * 16 + 64) ^ xm7;    // ks=1
  const int rAb = (wm * 128 + c) * 128;   // byte row base (+ mf*2048)
  const int rBb = (wn * 64 + c) * 128;    // byte row base (+ nf*2048)

  bf16x8 a0[4][2], a1[4][2], bq[4][2];

#define RD_A0(Abo)                                                                       \
  _Pragma("unroll") for (int mf = 0; mf < 4; ++mf) {                                     \
    a0[mf][0] = *(const bf16x8*)&smem_u16[((Abo) + rAb + mf * 2048 + ko0) >> 1];         \
    a0[mf][1] = *(const bf16x8*)&smem_u16[((Abo) + rAb + mf * 2048 + ko1) >> 1];         \
  }
#define RD_A1(Abo)                                                                       \
  _Pragma("unroll") for (int mf = 0; mf < 4; ++mf) {                                     \
    a1[mf][0] = *(const bf16x8*)&smem_u16[((Abo) + rAb + (mf + 4) * 2048 + ko0) >> 1];   \
    a1[mf][1] = *(const bf16x8*)&smem_u16[((Abo) + rAb + (mf + 4) * 2048 + ko1) >> 1];   \
  }
#define RD_BLO(Bbo)                                                                      \
  _Pragma("unroll") for (int nf = 0; nf < 2; ++nf) {                                     \
    bq[nf][0] = *(const bf16x8*)&smem_u16[((Bbo) + rBb + nf * 2048 + ko0) >> 1];         \
    bq[nf][1] = *(const bf16x8*)&smem_u16[((Bbo) + rBb + nf * 2048 + ko1) >> 1];         \
  }
#define RD_BHI(Bbo)                                                                      \
  _Pragma("unroll") for (int nf = 2; nf < 4; ++nf) {                                     \
    bq[nf][0] = *(const bf16x8*)&smem_u16[((Bbo) + rBb + nf * 2048 + ko0) >> 1];         \
    bq[nf][1] = *(const bf16x8*)&smem_u16[((Bbo) + rBb + nf * 2048 + ko1) >> 1];         \
  }
#define MFMA_Q(am, bl, bh, mo)                                                           \
  __builtin_amdgcn_s_setprio(1);                                                         \
  _Pragma("unroll") for (int mf = 0; mf < 4; ++mf)                                       \
  _Pragma("unroll") for (int nf = (bl); nf < (bh); ++nf)                                 \
  _Pragma("unroll") for (int ks = 0; ks < 2; ++ks)                                       \
      acc[mf + (mo)][nf] =                                                               \
          __builtin_amdgcn_mfma_f32_16x16x32_bf16(am[mf][ks], bq[nf][ks], acc[mf + (mo)][nf], 0, 0, 0); \
  __builtin_amdgcn_s_setprio(0);                                                         \
  __builtin_amdgcn_sched_barrier(0)

  asm volatile("s_waitcnt vmcnt(8)" ::: "memory");  // tile 0 landed; tile 1 in flight
  __builtin_amdgcn_s_barrier();
  asm volatile("" ::: "memory");
  RD_A0(0);        // R1 for k=0 (buf0)
  RD_BLO(65536);

  const int nKT = K >> 6;
  for (int k = 0; k < nKT; ++k) {
    const int db = k & 1;
    const int Abo = db * 32768;
    const int Bbo = 65536 + db * 32768;
    const int nAbo = (db ^ 1) * 32768;
    const int nBbo = 65536 + (db ^ 1) * 32768;
    const int k2 = k + 2;
    const bool st = (k2 < nKT);

    // ---- P1: lgkm(0) [R1 done]; issue R2=b_hi; MFMA Q11
    asm volatile("s_waitcnt lgkmcnt(0)" ::: "memory");
    RD_BHI(Bbo);
    MFMA_Q(a0, 0, 2, 0);
    __builtin_amdgcn_s_barrier();
    asm volatile("" ::: "memory");

    // ---- P2: issue R3=a1; lgkm(8) [R2 done, R3 in flight]; stage A*0; MFMA Q12
    RD_A1(Abo);
    asm volatile("s_waitcnt lgkmcnt(8)" ::: "memory");
    if (st) { STG_A(db, 0, 0, k2); STG_A(db, 1, 0, k2); }
    MFMA_Q(a0, 2, 4, 0);
    __builtin_amdgcn_s_barrier();
    asm volatile("" ::: "memory");

    // ---- P3: lgkm(0) [R3 done]; stage B (all); MFMA Q21
    asm volatile("s_waitcnt lgkmcnt(0)" ::: "memory");
    if (st) { STG_B(db, 0, 0, k2); STG_B(db, 0, 1, k2); STG_B(db, 1, 0, k2); STG_B(db, 1, 1, k2); }
    MFMA_Q(a1, 0, 2, 4);
    __builtin_amdgcn_s_barrier();
    asm volatile("" ::: "memory");

    // ---- P4: stage A*1; boundary vmcnt+barrier; issue R1-next; MFMA Q22
    if (st) { STG_A(db, 0, 1, k2); STG_A(db, 1, 1, k2); }
    if (k < nKT - 2) {
      asm volatile("s_waitcnt vmcnt(8)" ::: "memory");  // tile k+1 landed, k+2 in flight
    } else if (k == nKT - 2) {
      asm volatile("s_waitcnt vmcnt(0)" ::: "memory");  // last tile landed
    }
    __builtin_amdgcn_s_barrier();
    asm volatile("" ::: "memory");
    if (k + 1 < nKT) { RD_A0(nAbo); RD_BLO(nBbo); }  // R1 for k+1 (safe: tile landed)
    MFMA_Q(a1, 2, 4, 4);
    __builtin_amdgcn_s_barrier();
    asm volatile("" ::: "memory");
  }
#undef STG_A
#undef STG_B
#undef RD_A0
#undef RD_A1
#undef RD_BLO
#undef RD_BHI
#undef MFMA_Q

  if constexpr (EPI == 0) {
    const int which = n0 >> 10;  // 0=q 1=k 2=v (uniform: 1024 % 256 == 0)
    unsigned short* qk = (which == 0) ? qout : kout;
#pragma unroll
    for (int nf = 0; nf < 4; ++nf) {
      const int o = n0 + wn * 64 + nf * 16 + c;
      const int h = (o >> 6) & 15;
      const int d = o & 63;
      if (which < 2) {
        const float sgn = (d & 1) ? 1.0f : -1.0f;
        const float qscale = (which == 0) ? 0.125f : 1.0f;  // fold D^-0.5 into q
#pragma unroll
        for (int mf = 0; mf < 8; ++mf) {
          const int m = m0 + wm * 128 + mf * 16 + g * 4;
          const int bb = m >> 8;
          const int nb = m & 255;
          f32x4 v = acc[mf][nf];
          f32x4 p;
          p[0] = __shfl_xor(v[0], 1);
          p[1] = __shfl_xor(v[1], 1);
          p[2] = __shfl_xor(v[2], 1);
          p[3] = __shfl_xor(v[3], 1);
          size_t base = ((size_t)(bb * 16 + h) * 256 + nb) * 64 + d;
#pragma unroll
          for (int jj = 0; jj < 4; ++jj) {
            const int n = nb + jj;
            const float cv = cosT[n * 64 + d];
            const float sv = sinT[n * 64 + d];
            float ov = (v[jj] * cv + sgn * p[jj] * sv) * qscale;
            qk[base + (size_t)jj * 64] = f2bf(ov);
          }
        }
      } else {
#pragma unroll
        for (int mf = 0; mf < 8; ++mf) {
          const int m = m0 + wm * 128 + mf * 16 + g * 4;
          const int bb = m >> 8;
          const int nb = m & 255;
          f32x4 v = acc[mf][nf];
          u16x4 pk;
          pk[0] = f2bf(v[0]); pk[1] = f2bf(v[1]); pk[2] = f2bf(v[2]); pk[3] = f2bf(v[3]);
          size_t idx = ((size_t)(bb * 16 + h) * 64 + d) * 256 + nb;  // vT[b,h,d,n]
          *reinterpret_cast<u16x4*>(vTout + idx) = pk;
        }
      }
    }
  } else {
#pragma unroll
    for (int nf = 0; nf < 4; ++nf) {
      const int o = n0 + wn * 64 + nf * 16 + c;
      const float bv = bias[o];
#pragma unroll
      for (int mf = 0; mf < 8; ++mf) {
        const int m = m0 + wm * 128 + mf * 16 + g * 4;
        f32x4 v = acc[mf][nf];
#pragma unroll
        for (int jj = 0; jj < 4; ++jj) fout[(size_t)(m + jj) * N + o] = v[jj] + bv;
      }
    }
  }
}

// ---------------- flash attention, swapped operands (unchanged) ----------------
__global__ __launch_bounds__(256) void k_attn(const unsigned short* __restrict__ Q,
                                              const unsigned short* __restrict__ Kb,
                                              const unsigned short* __restrict__ VT,
                                              unsigned short* __restrict__ Out) {
  constexpr int LDK = 80, LDP = 80;
  __shared__ unsigned short klds[64 * LDK];
  __shared__ unsigned short plds[4][64 * LDP];
  const int bh = blockIdx.x;
  const int bb = bh >> 4, h = bh & 15;
  const int t = threadIdx.x, w = t >> 6, l = t & 63, c = l & 15, g = l >> 4;
  const unsigned short* qh = Q + (size_t)bh * 256 * 64;
  const unsigned short* kh = Kb + (size_t)bh * 256 * 64;
  const unsigned short* vh = VT + (size_t)bh * 64 * 256;
  const int q0 = w * 64;

  bf16x8 qf[4][2];
#pragma unroll
  for (int nf = 0; nf < 4; ++nf)
#pragma unroll
    for (int ks = 0; ks < 2; ++ks)
      qf[nf][ks] = *reinterpret_cast<const bf16x8*>(qh + (q0 + nf * 16 + c) * 64 + ks * 32 + g * 8);

  f32x4 oacc[4][4];
#pragma unroll
  for (int i = 0; i < 4; ++i)
#pragma unroll
    for (int jj = 0; jj < 4; ++jj) oacc[i][jj] = 0.0f;
  float mr[4] = {-1e30f, -1e30f, -1e30f, -1e30f};
  float lr[4] = {0.f, 0.f, 0.f, 0.f};

  for (int ch = 0; ch < 4; ++ch) {
    __syncthreads();
    {
      int row = t >> 3, col = (t & 7) * 8;
#pragma unroll
      for (int rep = 0; rep < 2; ++rep) {
        int r = rep * 32 + row;
        bf16x8 kv = *reinterpret_cast<const bf16x8*>(kh + (ch * 64 + r) * 64 + col);
        *reinterpret_cast<bf16x8*>(&klds[r * LDK + col]) = kv;
      }
    }
    __syncthreads();

    f32x4 s[4][4];
#pragma unroll
    for (int i = 0; i < 4; ++i)
#pragma unroll
      for (int jj = 0; jj < 4; ++jj) s[i][jj] = 0.0f;
#pragma unroll
    for (int ks = 0; ks < 2; ++ks) {
      bf16x8 kf[4];
#pragma unroll
      for (int mf = 0; mf < 4; ++mf)
        kf[mf] = *reinterpret_cast<const bf16x8*>(&klds[(mf * 16 + c) * LDK + ks * 32 + g * 8]);
#pragma unroll
      for (int mf = 0; mf < 4; ++mf)
#pragma unroll
        for (int nf = 0; nf < 4; ++nf)
          s[mf][nf] = __builtin_amdgcn_mfma_f32_16x16x32_bf16(kf[mf], qf[nf][ks], s[mf][nf], 0, 0, 0);
    }

#pragma unroll
    for (int nf = 0; nf < 4; ++nf) {
      float mx = -1e30f;
#pragma unroll
      for (int mf = 0; mf < 4; ++mf)
#pragma unroll
        for (int jj = 0; jj < 4; ++jj) mx = fmaxf(mx, s[mf][nf][jj]);
      mx = fmaxf(mx, __shfl_xor(mx, 16));
      mx = fmaxf(mx, __shfl_xor(mx, 32));
      float mnew = fmaxf(mr[nf], mx);
      float rsc = __expf(mr[nf] - mnew);
      mr[nf] = mnew;
      float sum = 0.f;
#pragma unroll
      for (int mf = 0; mf < 4; ++mf)
#pragma unroll
        for (int jj = 0; jj < 4; ++jj) {
          float p = __expf(s[mf][nf][jj] - mnew);
          s[mf][nf][jj] = p;
          sum += p;
        }
      sum += __shfl_xor(sum, 16);
      sum += __shfl_xor(sum, 32);
      lr[nf] = lr[nf] * rsc + sum;
#pragma unroll
      for (int mf = 0; mf < 4; ++mf) oacc[mf][nf] *= rsc;
    }

#pragma unroll
    for (int mf = 0; mf < 4; ++mf)
#pragma unroll
      for (int nf = 0; nf < 4; ++nf) {
        bf16x4 pk;
        pk[0] = (short)f2bf(s[mf][nf][0]);
        pk[1] = (short)f2bf(s[mf][nf][1]);
        pk[2] = (short)f2bf(s[mf][nf][2]);
        pk[3] = (short)f2bf(s[mf][nf][3]);
        *reinterpret_cast<bf16x4*>(&plds[w][(nf * 16 + c) * LDP + mf * 16 + g * 4]) = pk;
      }

#pragma unroll
    for (int ks = 0; ks < 2; ++ks) {
      bf16x8 vf[4], pf[4];
#pragma unroll
      for (int mf = 0; mf < 4; ++mf)
        vf[mf] = *reinterpret_cast<const bf16x8*>(vh + (mf * 16 + c) * 256 + ch * 64 + ks * 32 + g * 8);
#pragma unroll
      for (int nf = 0; nf < 4; ++nf) {
        bf16x4 p0 = *reinterpret_cast<const bf16x4*>(&plds[w][(nf * 16 + c) * LDP + ks * 32 + g * 8]);
        bf16x4 p1 = *reinterpret_cast<const bf16x4*>(&plds[w][(nf * 16 + c) * LDP + ks * 32 + g * 8 + 4]);
        pf[nf] = __builtin_shufflevector(p0, p1, 0, 1, 2, 3, 4, 5, 6, 7);
      }
#pragma unroll
      for (int mf = 0; mf < 4; ++mf)
#pragma unroll
        for (int nf = 0; nf < 4; ++nf)
          oacc[mf][nf] = __builtin_amdgcn_mfma_f32_16x16x32_bf16(vf[mf], pf[nf], oacc[mf][nf], 0, 0, 0);
    }
  }

  float linv[4];
#pragma unroll
  for (int nf = 0; nf < 4; ++nf) linv[nf] = 1.0f / lr[nf];
#pragma unroll
  for (int mf = 0; mf < 4; ++mf)
#pragma unroll
    for (int nf = 0; nf < 4; ++nf) {
      f32x4 v = oacc[mf][nf];
      u16x4 pk;
      pk[0] = f2bf(v[0] * linv[nf]);
      pk[1] = f2bf(v[1] * linv[nf]);
      pk[2] = f2bf(v[2] * linv[nf]);
      pk[3] = f2bf(v[3] * linv[nf]);
      size_t row = (size_t)bb * 256 + q0 + nf * 16 + c;
      size_t idx = row * 1024 + (size_t)h * 64 + mf * 16 + g * 4;  // out[b,n, h*64+d]
      *reinterpret_cast<u16x4*>(Out + idx) = pk;
    }
}

extern "C" void kernel_launch(void* const* d_in, const int* in_sizes, int n_in,
                              void* d_out, int out_size, void* d_ws, size_t ws_size,
                              hipStream_t stream) {
  const float* x = (const float*)d_in[0];
  const float* wqkv = (const float*)d_in[1];
  const float* wproj = (const float*)d_in[2];
  const float* bproj = (const float*)d_in[3];

  char* ws = (char*)d_ws;
  unsigned short* xb = (unsigned short*)(ws);                 // 33,554,432 B (reused as attn_out)
  unsigned short* wqkvb = (unsigned short*)(ws + 33554432);   //  6,291,456 B
  unsigned short* wprojb = (unsigned short*)(ws + 39845888);  //  2,097,152 B
  float* cosT = (float*)(ws + 41943040);                      //     65,536 B
  float* sinT = (float*)(ws + 42008576);                      //     65,536 B
  unsigned short* qb = (unsigned short*)(ws + 42074112);      // 33,554,432 B
  unsigned short* kb = (unsigned short*)(ws + 75628544);      // 33,554,432 B
  unsigned short* vtb = (unsigned short*)(ws + 109182976);    // 33,554,432 B -> total 142,737,408 B
  unsigned short* attn_out = xb;

  k_cvt<<<16384, 256, 0, stream>>>(x, xb, 4194304);
  k_cvt<<<3072, 256, 0, stream>>>(wqkv, wqkvb, 786432);
  k_cvt<<<1024, 256, 0, stream>>>(wproj, wprojb, 262144);
  k_tables<<<1, 256, 0, stream>>>(cosT, sinT);

  // QKV: M=16384 (64 tiles), N=3072 (12 tiles), K=1024; RoPE epilogue. grid=768 (%8==0)
  k_gemm<0><<<64 * 12, 512, 0, stream>>>(xb, wqkvb, 16384, 3072, 1024, 64,
                                         cosT, sinT, qb, kb, vtb, nullptr, nullptr);
  // attention: one block per (b,h)
  k_attn<<<1024, 256, 0, stream>>>(qb, kb, vtb, attn_out);
  // proj: M=16384 (64 tiles), N=1024 (4 tiles), K=1024, +bias, fp32 out. grid=256 (%8==0)
  k_gemm<1><<<64 * 4, 512, 0, stream>>>(attn_out, wprojb, 16384, 1024, 1024, 64,
                                        nullptr, nullptr, nullptr, nullptr, nullptr,
                                        bproj, (float*)d_out);
}

// Round 8
// 275.238 us; speedup vs baseline: 1.3128x; 1.0260x over previous
//
#include <hip/hip_runtime.h>
#include <stdint.h>

typedef __attribute__((ext_vector_type(8))) short bf16x8;
typedef __attribute__((ext_vector_type(4))) short bf16x4;
typedef __attribute__((ext_vector_type(4))) float f32x4;
typedef __attribute__((ext_vector_type(4))) unsigned short u16x4;

typedef __attribute__((address_space(3))) unsigned short lds_u16;
typedef const __attribute__((address_space(1))) unsigned short glb_u16;

__device__ __forceinline__ unsigned short f2bf(float f) {
  union { float f; unsigned u; } x; x.f = f;
  unsigned r = x.u + 0x7FFFu + ((x.u >> 16) & 1u);
  return (unsigned short)(r >> 16);
}

// ---------------- fused prep: 3x fp32->bf16 cvt + RoPE tables, one dispatch ----------------
__global__ __launch_bounds__(256) void k_prep(const float* __restrict__ x,
                                              const float* __restrict__ wqkv,
                                              const float* __restrict__ wproj,
                                              unsigned short* __restrict__ xb,
                                              unsigned short* __restrict__ wqkvb,
                                              unsigned short* __restrict__ wprojb,
                                              float* __restrict__ cosT, float* __restrict__ sinT) {
  const int b = blockIdx.x;
  const float* in;
  unsigned short* out;
  int i;
  if (b < 16384) {
    in = x; out = xb; i = b * 256 + threadIdx.x;
  } else if (b < 16384 + 3072) {
    in = wqkv; out = wqkvb; i = (b - 16384) * 256 + threadIdx.x;
  } else if (b < 16384 + 3072 + 1024) {
    in = wproj; out = wprojb; i = (b - 16384 - 3072) * 256 + threadIdx.x;
  } else {
    // tables block: F[n][d] = (d<32 ? n>>4 : n&15) * 10000^(-((d&31)>>1)/16)
    int n = threadIdx.x;
    int r = n >> 4, cc = n & 15;
    for (int d = 0; d < 64; ++d) {
      int tpos = (d < 32) ? r : cc;
      int j = (d & 31) >> 1;
      float ang = (float)tpos * powf(10000.0f, -(float)j * (1.0f / 16.0f));
      cosT[n * 64 + d] = cosf(ang);
      sinT[n * 64 + d] = sinf(ang);
    }
    return;
  }
  f32x4 v = reinterpret_cast<const f32x4*>(in)[i];
  u16x4 o;
  o[0] = f2bf(v[0]); o[1] = f2bf(v[1]); o[2] = f2bf(v[2]); o[3] = f2bf(v[3]);
  reinterpret_cast<u16x4*>(out)[i] = o;
}

// ============ 256x256xBK64, 8-wave (2x4), pipelined-read phase GEMM ============
// LDS swizzle: physical 16B-slot = logical_slot ^ (row&7) (all 32 banks per b128 read;
// bank conflicts measured 0). Pre-swizzled global source + XOR on ds_read address.
// Schedule: reads one phase ahead (R1=a0+b_lo prev-P4; R2=b_hi P1; R3=a1 P2); counted
// lgkm; stages one phase after the covering lgkm-wait; boundary vmcnt(8). No blanket
// sched_barrier pinning (m141 lesson) — compiler owns intra-phase ordering; asm
// "memory" clobbers keep the counted waits exact; one pin in P4 keeps R1 issue early.
template <int EPI>
__global__ __launch_bounds__(512, 2) void k_gemm(
    const unsigned short* __restrict__ A,  // M x K bf16
    const unsigned short* __restrict__ B,  // N x K bf16 (B^T layout)
    int M, int N, int K, int nTM,
    const float* __restrict__ cosT, const float* __restrict__ sinT,
    unsigned short* __restrict__ qout, unsigned short* __restrict__ kout,
    unsigned short* __restrict__ vTout,
    const float* __restrict__ bias, float* __restrict__ fout) {
  __shared__ unsigned short smem_u16[65536];  // 128 KiB

  const int t = threadIdx.x, w = t >> 6, l = t & 63, c = l & 15, g = l >> 4;
  const int wm = w >> 2, wn = w & 3;

  // L2-locality mapping: each XCD owns an A-band of nTM/8 row-tiles, tn fastest.
  const int nwg = gridDim.x;
  const int bid = (int)blockIdx.x;
  const int nTN = nwg / nTM;
  const int xcd = bid & 7;
  const int j = bid >> 3;
  const int tn = j % nTN;
  const int tm = xcd * (nTM >> 3) + j / nTN;
  const int m0 = tm * 256, n0 = tn * 256;

  // ---- stage source (pre-swizzled): thread t covers one 16B chunk of an 8192B issue.
  const int rS = t >> 3;                                 // row 0..63 within chunk
  const int colS = (((t & 7) ^ ((t >> 3) & 7)) * 8);     // element col (pre-swizzled)
  const unsigned short* Asrc = A + (size_t)(m0 + rS) * K + colS;
  const unsigned short* Bsrc = B + (size_t)(n0 + rS) * K + colS;
  const size_t hK = (size_t)128 * K;  // half-tile row skip
  const size_t iK = (size_t)64 * K;   // chunk row skip

#define STG_A(db, half, i, kt)                                                              \
  __builtin_amdgcn_global_load_lds((glb_u16*)(Asrc + (half) * hK + (i) * iK + (kt) * 64),   \
      (lds_u16*)&smem_u16[((db) * 32768 + (half) * 16384 + (i) * 8192 + w * 1024) >> 1],    \
      16, 0, 0)
#define STG_B(db, half, i, kt)                                                                      \
  __builtin_amdgcn_global_load_lds((glb_u16*)(Bsrc + (half) * hK + (i) * iK + (kt) * 64),           \
      (lds_u16*)&smem_u16[(65536 + (db) * 32768 + (half) * 16384 + (i) * 8192 + w * 1024) >> 1],    \
      16, 0, 0)

  // prologue: stage K-tiles 0 (buf0) and 1 (buf1) = 16 loads/wave
#pragma unroll
  for (int kk = 0; kk < 2; ++kk) {
    STG_A(kk, 0, 0, kk); STG_A(kk, 0, 1, kk); STG_A(kk, 1, 0, kk); STG_A(kk, 1, 1, kk);
    STG_B(kk, 0, 0, kk); STG_B(kk, 0, 1, kk); STG_B(kk, 1, 0, kk); STG_B(kk, 1, 1, kk);
  }

  f32x4 acc[8][4];
#pragma unroll
  for (int i = 0; i < 8; ++i)
#pragma unroll
    for (int jj = 0; jj < 4; ++jj) acc[i][jj] = 0.0f;

  // ---- fragment read addressing: physical byte = logical kbyte ^ ((row&7)<<4)
  const int xm7 = (c & 7) << 4;
  const int ko0 = (g * 16) ^ xm7;         // ks=0 byte offset within 128B row
  const int ko1 = (g * 16 + 64) ^ xm7;    // ks=1
  const int rAb = (wm * 128 + c) * 128;   // byte row base (+ mf*2048)
  const int rBb = (wn * 64 + c) * 128;    // byte row base (+ nf*2048)

  bf16x8 a0[4][2], a1[4][2], bq[4][2];

#define RD_A0(Abo)                                                                       \
  _Pragma("unroll") for (int mf = 0; mf < 4; ++mf) {                                     \
    a0[mf][0] = *(const bf16x8*)&smem_u16[((Abo) + rAb + mf * 2048 + ko0) >> 1];         \
    a0[mf][1] = *(const bf16x8*)&smem_u16[((Abo) + rAb + mf * 2048 + ko1) >> 1];         \
  }
#define RD_A1(Abo)                                                                       \
  _Pragma("unroll") for (int mf = 0; mf < 4; ++mf) {                                     \
    a1[mf][0] = *(const bf16x8*)&smem_u16[((Abo) + rAb + (mf + 4) * 2048 + ko0) >> 1];   \
    a1[mf][1] = *(const bf16x8*)&smem_u16[((Abo) + rAb + (mf + 4) * 2048 + ko1) >> 1];   \
  }
#define RD_BLO(Bbo)                                                                      \
  _Pragma("unroll") for (int nf = 0; nf < 2; ++nf) {                                     \
    bq[nf][0] = *(const bf16x8*)&smem_u16[((Bbo) + rBb + nf * 2048 + ko0) >> 1];         \
    bq[nf][1] = *(const bf16x8*)&smem_u16[((Bbo) + rBb + nf * 2048 + ko1) >> 1];         \
  }
#define RD_BHI(Bbo)                                                                      \
  _Pragma("unroll") for (int nf = 2; nf < 4; ++nf) {                                     \
    bq[nf][0] = *(const bf16x8*)&smem_u16[((Bbo) + rBb + nf * 2048 + ko0) >> 1];         \
    bq[nf][1] = *(const bf16x8*)&smem_u16[((Bbo) + rBb + nf * 2048 + ko1) >> 1];         \
  }
#define MFMA_Q(am, bl, bh, mo)                                                           \
  __builtin_amdgcn_s_setprio(1);                                                         \
  _Pragma("unroll") for (int mf = 0; mf < 4; ++mf)                                       \
  _Pragma("unroll") for (int nf = (bl); nf < (bh); ++nf)                                 \
  _Pragma("unroll") for (int ks = 0; ks < 2; ++ks)                                       \
      acc[mf + (mo)][nf] =                                                               \
          __builtin_amdgcn_mfma_f32_16x16x32_bf16(am[mf][ks], bq[nf][ks], acc[mf + (mo)][nf], 0, 0, 0); \
  __builtin_amdgcn_s_setprio(0)

  asm volatile("s_waitcnt vmcnt(8)" ::: "memory");  // tile 0 landed; tile 1 in flight
  __builtin_amdgcn_s_barrier();
  asm volatile("" ::: "memory");
  RD_A0(0);        // R1 for k=0 (buf0)
  RD_BLO(65536);

  const int nKT = K >> 6;
  for (int k = 0; k < nKT; ++k) {
    const int db = k & 1;
    const int Abo = db * 32768;
    const int Bbo = 65536 + db * 32768;
    const int nAbo = (db ^ 1) * 32768;
    const int nBbo = 65536 + (db ^ 1) * 32768;
    const int k2 = k + 2;
    const bool st = (k2 < nKT);

    // ---- P1: lgkm(0) [R1 done]; issue R2=b_hi; MFMA Q11
    asm volatile("s_waitcnt lgkmcnt(0)" ::: "memory");
    RD_BHI(Bbo);
    MFMA_Q(a0, 0, 2, 0);
    __builtin_amdgcn_s_barrier();
    asm volatile("" ::: "memory");

    // ---- P2: issue R3=a1; lgkm(8) [R2 done, R3 in flight]; stage A*0; MFMA Q12
    RD_A1(Abo);
    asm volatile("s_waitcnt lgkmcnt(8)" ::: "memory");
    if (st) { STG_A(db, 0, 0, k2); STG_A(db, 1, 0, k2); }
    MFMA_Q(a0, 2, 4, 0);
    __builtin_amdgcn_s_barrier();
    asm volatile("" ::: "memory");

    // ---- P3: lgkm(0) [R3 done]; stage B (all); MFMA Q21
    asm volatile("s_waitcnt lgkmcnt(0)" ::: "memory");
    if (st) { STG_B(db, 0, 0, k2); STG_B(db, 0, 1, k2); STG_B(db, 1, 0, k2); STG_B(db, 1, 1, k2); }
    MFMA_Q(a1, 0, 2, 4);
    __builtin_amdgcn_s_barrier();
    asm volatile("" ::: "memory");

    // ---- P4: stage A*1; boundary vmcnt+barrier; issue R1-next (pinned early); MFMA Q22
    if (st) { STG_A(db, 0, 1, k2); STG_A(db, 1, 1, k2); }
    if (k < nKT - 2) {
      asm volatile("s_waitcnt vmcnt(8)" ::: "memory");  // tile k+1 landed, k+2 in flight
    } else if (k == nKT - 2) {
      asm volatile("s_waitcnt vmcnt(0)" ::: "memory");  // last tile landed
    }
    __builtin_amdgcn_s_barrier();
    asm volatile("" ::: "memory");
    if (k + 1 < nKT) { RD_A0(nAbo); RD_BLO(nBbo); }  // R1 for k+1 (safe: tile landed)
    __builtin_amdgcn_sched_barrier(0);               // keep R1 issue ahead of Q22
    MFMA_Q(a1, 2, 4, 4);
    __builtin_amdgcn_s_barrier();
    asm volatile("" ::: "memory");
  }
#undef STG_A
#undef STG_B
#undef RD_A0
#undef RD_A1
#undef RD_BLO
#undef RD_BHI
#undef MFMA_Q

  if constexpr (EPI == 0) {
    const int which = n0 >> 10;  // 0=q 1=k 2=v (uniform: 1024 % 256 == 0)
    unsigned short* qk = (which == 0) ? qout : kout;
#pragma unroll
    for (int nf = 0; nf < 4; ++nf) {
      const int o = n0 + wn * 64 + nf * 16 + c;
      const int h = (o >> 6) & 15;
      const int d = o & 63;
      if (which < 2) {
        const float sgn = (d & 1) ? 1.0f : -1.0f;
        const float qscale = (which == 0) ? 0.125f : 1.0f;  // fold D^-0.5 into q
#pragma unroll
        for (int mf = 0; mf < 8; ++mf) {
          const int m = m0 + wm * 128 + mf * 16 + g * 4;
          const int bb = m >> 8;
          const int nb = m & 255;
          f32x4 v = acc[mf][nf];
          f32x4 p;
          p[0] = __shfl_xor(v[0], 1);
          p[1] = __shfl_xor(v[1], 1);
          p[2] = __shfl_xor(v[2], 1);
          p[3] = __shfl_xor(v[3], 1);
          size_t base = ((size_t)(bb * 16 + h) * 256 + nb) * 64 + d;
#pragma unroll
          for (int jj = 0; jj < 4; ++jj) {
            const int n = nb + jj;
            const float cv = cosT[n * 64 + d];
            const float sv = sinT[n * 64 + d];
            float ov = (v[jj] * cv + sgn * p[jj] * sv) * qscale;
            qk[base + (size_t)jj * 64] = f2bf(ov);
          }
        }
      } else {
#pragma unroll
        for (int mf = 0; mf < 8; ++mf) {
          const int m = m0 + wm * 128 + mf * 16 + g * 4;
          const int bb = m >> 8;
          const int nb = m & 255;
          f32x4 v = acc[mf][nf];
          u16x4 pk;
          pk[0] = f2bf(v[0]); pk[1] = f2bf(v[1]); pk[2] = f2bf(v[2]); pk[3] = f2bf(v[3]);
          size_t idx = ((size_t)(bb * 16 + h) * 64 + d) * 256 + nb;  // vT[b,h,d,n]
          *reinterpret_cast<u16x4*>(vTout + idx) = pk;
        }
      }
    }
  } else {
#pragma unroll
    for (int nf = 0; nf < 4; ++nf) {
      const int o = n0 + wn * 64 + nf * 16 + c;
      const float bv = bias[o];
#pragma unroll
      for (int mf = 0; mf < 8; ++mf) {
        const int m = m0 + wm * 128 + mf * 16 + g * 4;
        f32x4 v = acc[mf][nf];
#pragma unroll
        for (int jj = 0; jj < 4; ++jj) fout[(size_t)(m + jj) * N + o] = v[jj] + bv;
      }
    }
  }
}

// ---------------- flash attention, swapped operands (unchanged) ----------------
__global__ __launch_bounds__(256) void k_attn(const unsigned short* __restrict__ Q,
                                              const unsigned short* __restrict__ Kb,
                                              const unsigned short* __restrict__ VT,
                                              unsigned short* __restrict__ Out) {
  constexpr int LDK = 80, LDP = 80;
  __shared__ unsigned short klds[64 * LDK];
  __shared__ unsigned short plds[4][64 * LDP];
  const int bh = blockIdx.x;
  const int bb = bh >> 4, h = bh & 15;
  const int t = threadIdx.x, w = t >> 6, l = t & 63, c = l & 15, g = l >> 4;
  const unsigned short* qh = Q + (size_t)bh * 256 * 64;
  const unsigned short* kh = Kb + (size_t)bh * 256 * 64;
  const unsigned short* vh = VT + (size_t)bh * 64 * 256;
  const int q0 = w * 64;

  bf16x8 qf[4][2];
#pragma unroll
  for (int nf = 0; nf < 4; ++nf)
#pragma unroll
    for (int ks = 0; ks < 2; ++ks)
      qf[nf][ks] = *reinterpret_cast<const bf16x8*>(qh + (q0 + nf * 16 + c) * 64 + ks * 32 + g * 8);

  f32x4 oacc[4][4];
#pragma unroll
  for (int i = 0; i < 4; ++i)
#pragma unroll
    for (int jj = 0; jj < 4; ++jj) oacc[i][jj] = 0.0f;
  float mr[4] = {-1e30f, -1e30f, -1e30f, -1e30f};
  float lr[4] = {0.f, 0.f, 0.f, 0.f};

  for (int ch = 0; ch < 4; ++ch) {
    __syncthreads();
    {
      int row = t >> 3, col = (t & 7) * 8;
#pragma unroll
      for (int rep = 0; rep < 2; ++rep) {
        int r = rep * 32 + row;
        bf16x8 kv = *reinterpret_cast<const bf16x8*>(kh + (ch * 64 + r) * 64 + col);
        *reinterpret_cast<bf16x8*>(&klds[r * LDK + col]) = kv;
      }
    }
    __syncthreads();

    f32x4 s[4][4];
#pragma unroll
    for (int i = 0; i < 4; ++i)
#pragma unroll
      for (int jj = 0; jj < 4; ++jj) s[i][jj] = 0.0f;
#pragma unroll
    for (int ks = 0; ks < 2; ++ks) {
      bf16x8 kf[4];
#pragma unroll
      for (int mf = 0; mf < 4; ++mf)
        kf[mf] = *reinterpret_cast<const bf16x8*>(&klds[(mf * 16 + c) * LDK + ks * 32 + g * 8]);
#pragma unroll
      for (int mf = 0; mf < 4; ++mf)
#pragma unroll
        for (int nf = 0; nf < 4; ++nf)
          s[mf][nf] = __builtin_amdgcn_mfma_f32_16x16x32_bf16(kf[mf], qf[nf][ks], s[mf][nf], 0, 0, 0);
    }

#pragma unroll
    for (int nf = 0; nf < 4; ++nf) {
      float mx = -1e30f;
#pragma unroll
      for (int mf = 0; mf < 4; ++mf)
#pragma unroll
        for (int jj = 0; jj < 4; ++jj) mx = fmaxf(mx, s[mf][nf][jj]);
      mx = fmaxf(mx, __shfl_xor(mx, 16));
      mx = fmaxf(mx, __shfl_xor(mx, 32));
      float mnew = fmaxf(mr[nf], mx);
      float rsc = __expf(mr[nf] - mnew);
      mr[nf] = mnew;
      float sum = 0.f;
#pragma unroll
      for (int mf = 0; mf < 4; ++mf)
#pragma unroll
        for (int jj = 0; jj < 4; ++jj) {
          float p = __expf(s[mf][nf][jj] - mnew);
          s[mf][nf][jj] = p;
          sum += p;
        }
      sum += __shfl_xor(sum, 16);
      sum += __shfl_xor(sum, 32);
      lr[nf] = lr[nf] * rsc + sum;
#pragma unroll
      for (int mf = 0; mf < 4; ++mf) oacc[mf][nf] *= rsc;
    }

#pragma unroll
    for (int mf = 0; mf < 4; ++mf)
#pragma unroll
      for (int nf = 0; nf < 4; ++nf) {
        bf16x4 pk;
        pk[0] = (short)f2bf(s[mf][nf][0]);
        pk[1] = (short)f2bf(s[mf][nf][1]);
        pk[2] = (short)f2bf(s[mf][nf][2]);
        pk[3] = (short)f2bf(s[mf][nf][3]);
        *reinterpret_cast<bf16x4*>(&plds[w][(nf * 16 + c) * LDP + mf * 16 + g * 4]) = pk;
      }

#pragma unroll
    for (int ks = 0; ks < 2; ++ks) {
      bf16x8 vf[4], pf[4];
#pragma unroll
      for (int mf = 0; mf < 4; ++mf)
        vf[mf] = *reinterpret_cast<const bf16x8*>(vh + (mf * 16 + c) * 256 + ch * 64 + ks * 32 + g * 8);
#pragma unroll
      for (int nf = 0; nf < 4; ++nf) {
        bf16x4 p0 = *reinterpret_cast<const bf16x4*>(&plds[w][(nf * 16 + c) * LDP + ks * 32 + g * 8]);
        bf16x4 p1 = *reinterpret_cast<const bf16x4*>(&plds[w][(nf * 16 + c) * LDP + ks * 32 + g * 8 + 4]);
        pf[nf] = __builtin_shufflevector(p0, p1, 0, 1, 2, 3, 4, 5, 6, 7);
      }
#pragma unroll
      for (int mf = 0; mf < 4; ++mf)
#pragma unroll
        for (int nf = 0; nf < 4; ++nf)
          oacc[mf][nf] = __builtin_amdgcn_mfma_f32_16x16x32_bf16(vf[mf], pf[nf], oacc[mf][nf], 0, 0, 0);
    }
  }

  float linv[4];
#pragma unroll
  for (int nf = 0; nf < 4; ++nf) linv[nf] = 1.0f / lr[nf];
#pragma unroll
  for (int mf = 0; mf < 4; ++mf)
#pragma unroll
    for (int nf = 0; nf < 4; ++nf) {
      f32x4 v = oacc[mf][nf];
      u16x4 pk;
      pk[0] = f2bf(v[0] * linv[nf]);
      pk[1] = f2bf(v[1] * linv[nf]);
      pk[2] = f2bf(v[2] * linv[nf]);
      pk[3] = f2bf(v[3] * linv[nf]);
      size_t row = (size_t)bb * 256 + q0 + nf * 16 + c;
      size_t idx = row * 1024 + (size_t)h * 64 + mf * 16 + g * 4;  // out[b,n, h*64+d]
      *reinterpret_cast<u16x4*>(Out + idx) = pk;
    }
}

extern "C" void kernel_launch(void* const* d_in, const int* in_sizes, int n_in,
                              void* d_out, int out_size, void* d_ws, size_t ws_size,
                              hipStream_t stream) {
  const float* x = (const float*)d_in[0];
  const float* wqkv = (const float*)d_in[1];
  const float* wproj = (const float*)d_in[2];
  const float* bproj = (const float*)d_in[3];

  char* ws = (char*)d_ws;
  unsigned short* xb = (unsigned short*)(ws);                 // 33,554,432 B (reused as attn_out)
  unsigned short* wqkvb = (unsigned short*)(ws + 33554432);   //  6,291,456 B
  unsigned short* wprojb = (unsigned short*)(ws + 39845888);  //  2,097,152 B
  float* cosT = (float*)(ws + 41943040);                      //     65,536 B
  float* sinT = (float*)(ws + 42008576);                      //     65,536 B
  unsigned short* qb = (unsigned short*)(ws + 42074112);      // 33,554,432 B
  unsigned short* kb = (unsigned short*)(ws + 75628544);      // 33,554,432 B
  unsigned short* vtb = (unsigned short*)(ws + 109182976);    // 33,554,432 B -> total 142,737,408 B
  unsigned short* attn_out = xb;

  // fused cvt(x) + cvt(wqkv) + cvt(wproj) + RoPE tables
  k_prep<<<16384 + 3072 + 1024 + 1, 256, 0, stream>>>(x, wqkv, wproj, xb, wqkvb, wprojb,
                                                      cosT, sinT);

  // QKV: M=16384 (64 tiles), N=3072 (12 tiles), K=1024; RoPE epilogue. grid=768 (%8==0)
  k_gemm<0><<<64 * 12, 512, 0, stream>>>(xb, wqkvb, 16384, 3072, 1024, 64,
                                         cosT, sinT, qb, kb, vtb, nullptr, nullptr);
  // attention: one block per (b,h)
  k_attn<<<1024, 256, 0, stream>>>(qb, kb, vtb, attn_out);
  // proj: M=16384 (64 tiles), N=1024 (4 tiles), K=1024, +bias, fp32 out. grid=256 (%8==0)
  k_gemm<1><<<64 * 4, 512, 0, stream>>>(attn_out, wprojb, 16384, 1024, 1024, 64,
                                        nullptr, nullptr, nullptr, nullptr, nullptr,
                                        bproj, (float*)d_out);
}